// Round 1
// baseline (28279.636 us; speedup 1.0000x reference)
//
#include <hip/hip_runtime.h>
#include <hip/hip_bf16.h>
#include <math.h>

#define TSEQ   2048
#define BATCH  2
#define DMODEL 1024
#define NLAYER 6
#define NHEAD  16
#define HDIM   64
#define DFFN   4096
#define NVOCAB 32000
#define LNEPS  1e-5f

// ----------------------------- embedding ---------------------------------
__global__ __launch_bounds__(256) void embed_kernel(
    const int* __restrict__ ids, const float* __restrict__ emb,
    const float* __restrict__ pos, float* __restrict__ x) {
  int bt  = blockIdx.x;            // b*T + t
  int t   = bt & (TSEQ - 1);
  int id  = ids[bt];
  int tid = threadIdx.x;
  float4 e = ((const float4*)(emb + (size_t)id * DMODEL))[tid];
  float4 p = ((const float4*)(pos + (size_t)t  * DMODEL))[tid];
  float4 r;
  r.x = e.x + p.x; r.y = e.y + p.y; r.z = e.z + p.z; r.w = e.w + p.w;
  ((float4*)(x + (size_t)bt * DMODEL))[tid] = r;
}

// ----------------------------- layernorm ---------------------------------
__global__ __launch_bounds__(256) void ln_kernel(
    const float* __restrict__ x, const float* __restrict__ g,
    const float* __restrict__ b, float* __restrict__ y) {
  int row = blockIdx.x, tid = threadIdx.x;
  int lane = tid & 63, w = tid >> 6;
  float4 v = ((const float4*)(x + (size_t)row * DMODEL))[tid];
  float s = v.x + v.y + v.z + v.w;
#pragma unroll
  for (int o = 32; o >= 1; o >>= 1) s += __shfl_xor(s, o);
  __shared__ float red[8];
  if (lane == 0) red[w] = s;
  __syncthreads();
  float mu = (red[0] + red[1] + red[2] + red[3]) * (1.0f / DMODEL);
  float d0 = v.x - mu, d1 = v.y - mu, d2 = v.z - mu, d3 = v.w - mu;
  float s2 = d0*d0 + d1*d1 + d2*d2 + d3*d3;
#pragma unroll
  for (int o = 32; o >= 1; o >>= 1) s2 += __shfl_xor(s2, o);
  if (lane == 0) red[4 + w] = s2;
  __syncthreads();
  float var = (red[4] + red[5] + red[6] + red[7]) * (1.0f / DMODEL);
  float rs = rsqrtf(var + LNEPS);
  float4 gv = ((const float4*)g)[tid];
  float4 bv = ((const float4*)b)[tid];
  float4 r;
  r.x = d0 * rs * gv.x + bv.x;
  r.y = d1 * rs * gv.y + bv.y;
  r.z = d2 * rs * gv.z + bv.z;
  r.w = d3 * rs * gv.w + bv.w;
  ((float4*)(y + (size_t)row * DMODEL))[tid] = r;
}

// ------------------------------- GEMM -------------------------------------
// C[M,N] = A[M,K] * W[N,K]^T  (+bias) (+gelu) (+res), all row-major fp32.
__device__ __forceinline__ float gelu_f(float v) {
  return 0.5f * v * (1.0f + erff(v * 0.70710678118654752f));
}

template<int ACT, bool BIAS, bool RES>
__global__ __launch_bounds__(256) void gemm_kernel(
    const float* __restrict__ A, const float* __restrict__ W,
    const float* __restrict__ bias, const float* __restrict__ res,
    float* __restrict__ C, int M, int N, int K) {
  constexpr int BK = 16, LDT = 128 + 4;           // pad 4: float4-aligned, 2-way max
  __shared__ float As[BK][LDT];
  __shared__ float Ws[BK][LDT];
  int tid = threadIdx.x;
  int tx = tid & 15, ty = tid >> 4;
  int m0 = blockIdx.y * 128, n0 = blockIdx.x * 128;
  int sr = tid >> 2;                               // 0..63: staging row
  int sc = (tid & 3) << 2;                         // 0,4,8,12: staging k-col
  const float* Ap = A + (size_t)(m0 + sr) * K + sc;
  const float* Wp = W + (size_t)(n0 + sr) * K + sc;
  float acc[8][8] = {};
  for (int k0 = 0; k0 < K; k0 += BK) {
    float4 a0 = *(const float4*)(Ap + k0);
    float4 a1 = *(const float4*)(Ap + (size_t)64 * K + k0);
    float4 w0 = *(const float4*)(Wp + k0);
    float4 w1 = *(const float4*)(Wp + (size_t)64 * K + k0);
    __syncthreads();
    As[sc+0][sr]    = a0.x; As[sc+1][sr]    = a0.y; As[sc+2][sr]    = a0.z; As[sc+3][sr]    = a0.w;
    As[sc+0][sr+64] = a1.x; As[sc+1][sr+64] = a1.y; As[sc+2][sr+64] = a1.z; As[sc+3][sr+64] = a1.w;
    Ws[sc+0][sr]    = w0.x; Ws[sc+1][sr]    = w0.y; Ws[sc+2][sr]    = w0.z; Ws[sc+3][sr]    = w0.w;
    Ws[sc+0][sr+64] = w1.x; Ws[sc+1][sr+64] = w1.y; Ws[sc+2][sr+64] = w1.z; Ws[sc+3][sr+64] = w1.w;
    __syncthreads();
#pragma unroll
    for (int k = 0; k < BK; ++k) {
      float4 aA = *(const float4*)&As[k][ty << 2];
      float4 aB = *(const float4*)&As[k][64 + (ty << 2)];
      float4 bA = *(const float4*)&Ws[k][tx << 2];
      float4 bB = *(const float4*)&Ws[k][64 + (tx << 2)];
      float av[8] = {aA.x, aA.y, aA.z, aA.w, aB.x, aB.y, aB.z, aB.w};
      float bv[8] = {bA.x, bA.y, bA.z, bA.w, bB.x, bB.y, bB.z, bB.w};
#pragma unroll
      for (int i = 0; i < 8; ++i)
#pragma unroll
        for (int j = 0; j < 8; ++j)
          acc[i][j] += av[i] * bv[j];
    }
  }
#pragma unroll
  for (int i = 0; i < 8; ++i) {
    int row = m0 + ((i < 4) ? (ty * 4 + i) : (64 + ty * 4 + i - 4));
#pragma unroll
    for (int jh = 0; jh < 2; ++jh) {
      int col = n0 + jh * 64 + tx * 4;
      float vv[4];
#pragma unroll
      for (int j = 0; j < 4; ++j) {
        float u = acc[i][jh * 4 + j];
        if (BIAS) u += bias[col + j];
        if (ACT == 1) u = gelu_f(u);
        if (RES) u += res[(size_t)row * N + col + j];
        vv[j] = u;
      }
      float4 o; o.x = vv[0]; o.y = vv[1]; o.z = vv[2]; o.w = vv[3];
      *(float4*)(C + (size_t)row * N + col) = o;
    }
  }
}

// --------------------------- flash attention ------------------------------
// qkv layout: [B*T, 3*D], e = c*1024 + h*64 + hd. Block: one (b,h), 32 q-rows
// (4 waves x 8 rows). K staged transposed [d][s] (pad 65), V row-major [s][d]
// (pad 68). Online softmax in fp32.
__global__ __launch_bounds__(256) void attn_kernel(
    const float* __restrict__ qkv, float* __restrict__ out) {
  int qt = blockIdx.x;                 // 0..T/32-1
  int bh = blockIdx.y;                 // 0..B*H-1
  int b = bh >> 4, h = bh & 15;
  int t0 = qt * 32;
  int tid = threadIdx.x;
  int lane = tid & 63, w = tid >> 6;
  __shared__ float kT[HDIM][65];
  __shared__ float vs[64][68];
  const float* qkv_b = qkv + (size_t)b * TSEQ * 3 * DMODEL;

  float q[8], o[8], m[8], l[8];
#pragma unroll
  for (int r = 0; r < 8; ++r) {
    int t = t0 + w * 8 + r;
    q[r] = qkv_b[(size_t)t * (3 * DMODEL) + h * HDIM + lane] * 0.125f;  // HD^-0.5
    o[r] = 0.f; m[r] = -1e30f; l[r] = 0.f;
  }
  int nt = (t0 + 32 + 63) >> 6;
  int sr = tid >> 2;                   // staging row 0..63
  int sc = (tid & 3) << 4;             // staging col group

  for (int st = 0; st < nt; ++st) {
    int s0 = st << 6;
    __syncthreads();                   // protect prev-iter LDS reads
    const float* krow = qkv_b + (size_t)(s0 + sr) * (3 * DMODEL) + DMODEL + h * HDIM;
    const float* vrow = krow + DMODEL;
#pragma unroll
    for (int c = 0; c < 16; c += 4) {
      float4 kv = *(const float4*)(krow + sc + c);
      kT[sc + c + 0][sr] = kv.x; kT[sc + c + 1][sr] = kv.y;
      kT[sc + c + 2][sr] = kv.z; kT[sc + c + 3][sr] = kv.w;
      *(float4*)&vs[sr][sc + c] = *(const float4*)(vrow + sc + c);
    }
    __syncthreads();

    // scores: lane = k-index j; s_j[r] = q_r . k_{s0+j}
    float scr[8] = {0, 0, 0, 0, 0, 0, 0, 0};
    for (int d = 0; d < HDIM; ++d) {
      float kd = kT[d][lane];
#pragma unroll
      for (int r = 0; r < 8; ++r) scr[r] += __shfl(q[r], d) * kd;
    }
    if (s0 + 63 > t0) {                // diagonal region: causal mask
#pragma unroll
      for (int r = 0; r < 8; ++r)
        if (s0 + lane > t0 + w * 8 + r) scr[r] = -3e38f;
    }
    // online softmax
    float p_[8];
#pragma unroll
    for (int r = 0; r < 8; ++r) {
      float tm = scr[r];
#pragma unroll
      for (int off = 32; off >= 1; off >>= 1) tm = fmaxf(tm, __shfl_xor(tm, off));
      float mn = fmaxf(m[r], tm);
      float p = expf(scr[r] - mn);     // masked: exp(-3e38 - mn) = 0
      float alpha = expf(m[r] - mn);   // first tile: exp(-1e30 - mn) = 0
      m[r] = mn;
      float ps = p;
#pragma unroll
      for (int off = 32; off >= 1; off >>= 1) ps += __shfl_xor(ps, off);
      l[r] = l[r] * alpha + ps;
      o[r] *= alpha;
      p_[r] = p;
    }
    // PV: lane = dim d; o_r[d] += sum_j p_j * v[j][d]
    for (int j = 0; j < 64; ++j) {
      float vv = vs[j][lane];
#pragma unroll
      for (int r = 0; r < 8; ++r) o[r] += __shfl(p_[r], j) * vv;
    }
  }
#pragma unroll
  for (int r = 0; r < 8; ++r) {
    int t = t0 + w * 8 + r;
    out[(size_t)(b * TSEQ + t) * DMODEL + h * HDIM + lane] = o[r] / l[r];
  }
}

// ------------------------------ launcher ----------------------------------
extern "C" void kernel_launch(void* const* d_in, const int* in_sizes, int n_in,
                              void* d_out, int out_size, void* d_ws, size_t ws_size,
                              hipStream_t stream) {
  const int*   ids    = (const int*)d_in[0];
  const float* emb    = (const float*)d_in[1];
  const float* pos    = (const float*)d_in[2];
  const float* ln1_g  = (const float*)d_in[3];
  const float* ln1_b  = (const float*)d_in[4];
  const float* ln2_g  = (const float*)d_in[5];
  const float* ln2_b  = (const float*)d_in[6];
  const float* qkv_w  = (const float*)d_in[7];
  const float* out_w  = (const float*)d_in[8];
  const float* mlp_w1 = (const float*)d_in[9];
  const float* mlp_b1 = (const float*)d_in[10];
  const float* mlp_w2 = (const float*)d_in[11];
  const float* mlp_b2 = (const float*)d_in[12];
  const float* lnf_g  = (const float*)d_in[13];
  const float* lnf_b  = (const float*)d_in[14];
  float* outp = (float*)d_out;

  const int M = BATCH * TSEQ;                       // 4096
  float* x    = (float*)d_ws;                       // [M, D]
  float* y    = x    + (size_t)M * DMODEL;          // [M, D]   (LN out / attn out)
  float* qkvb = y    + (size_t)M * DMODEL;          // [M, 3D]
  float* mid  = qkvb + (size_t)M * 3 * DMODEL;      // [M, DFF]

  embed_kernel<<<M, 256, 0, stream>>>(ids, emb, pos, x);

  for (int l = 0; l < NLAYER; ++l) {
    ln_kernel<<<M, 256, 0, stream>>>(x, ln1_g + l * DMODEL, ln1_b + l * DMODEL, y);
    gemm_kernel<0, false, false><<<dim3(3 * DMODEL / 128, M / 128), 256, 0, stream>>>(
        y, qkv_w + (size_t)l * 3 * DMODEL * DMODEL, nullptr, nullptr, qkvb,
        M, 3 * DMODEL, DMODEL);
    attn_kernel<<<dim3(TSEQ / 32, BATCH * NHEAD), 256, 0, stream>>>(qkvb, y);
    gemm_kernel<0, false, true><<<dim3(DMODEL / 128, M / 128), 256, 0, stream>>>(
        y, out_w + (size_t)l * DMODEL * DMODEL, nullptr, x, x, M, DMODEL, DMODEL);
    ln_kernel<<<M, 256, 0, stream>>>(x, ln2_g + l * DMODEL, ln2_b + l * DMODEL, y);
    gemm_kernel<1, true, false><<<dim3(DFFN / 128, M / 128), 256, 0, stream>>>(
        y, mlp_w1 + (size_t)l * DFFN * DMODEL, mlp_b1 + (size_t)l * DFFN, nullptr, mid,
        M, DFFN, DMODEL);
    gemm_kernel<0, true, true><<<dim3(DMODEL / 128, M / 128), 256, 0, stream>>>(
        mid, mlp_w2 + (size_t)l * DMODEL * DFFN, mlp_b2 + (size_t)l * DMODEL, x, x,
        M, DMODEL, DFFN);
  }
  ln_kernel<<<M, 256, 0, stream>>>(x, lnf_g, lnf_b, y);
  gemm_kernel<0, false, false><<<dim3(NVOCAB / 128, M / 128), 256, 0, stream>>>(
      y, emb, nullptr, nullptr, outp, M, NVOCAB, DMODEL);
}

// Round 2
// 18101.166 us; speedup vs baseline: 1.5623x; 1.5623x over previous
//
#include <hip/hip_runtime.h>
#include <math.h>

#define TSEQ   2048
#define BATCH  2
#define DMODEL 1024
#define NLAYER 6
#define NHEAD  16
#define HDIM   64
#define DFFN   4096
#define NVOCAB 32000
#define LNEPS  1e-5f

typedef __bf16 bf16_t;
typedef bf16_t bf16x8 __attribute__((ext_vector_type(8)));
typedef float  f32x4  __attribute__((ext_vector_type(4)));
typedef unsigned short u16;
typedef u16 u16x4 __attribute__((ext_vector_type(4)));
typedef u16 u16x8 __attribute__((ext_vector_type(8)));

__device__ __forceinline__ u16 f2bf(float f) {   // RNE fp32 -> bf16 bits
  unsigned u = __float_as_uint(f);
  return (u16)((u + 0x7fffu + ((u >> 16) & 1u)) >> 16);
}

__device__ __forceinline__ void gload16(const void* g, void* l) {
  __builtin_amdgcn_global_load_lds(
      (const __attribute__((address_space(1))) unsigned int*)g,
      (__attribute__((address_space(3))) unsigned int*)l, 16, 0, 0);
}

// ----------------------------- embedding ---------------------------------
__global__ __launch_bounds__(256) void embed_kernel(
    const int* __restrict__ ids, const float* __restrict__ emb,
    const float* __restrict__ pos, float* __restrict__ x) {
  int bt  = blockIdx.x;
  int t   = bt & (TSEQ - 1);
  int id  = ids[bt];
  int tid = threadIdx.x;
  float4 e = ((const float4*)(emb + (size_t)id * DMODEL))[tid];
  float4 p = ((const float4*)(pos + (size_t)t  * DMODEL))[tid];
  float4 r;
  r.x = e.x + p.x; r.y = e.y + p.y; r.z = e.z + p.z; r.w = e.w + p.w;
  ((float4*)(x + (size_t)bt * DMODEL))[tid] = r;
}

// ------------------------- fp32 -> bf16 convert ---------------------------
__global__ __launch_bounds__(256) void cvt_bf16_kernel(
    const float* __restrict__ in, u16* __restrict__ out) {
  size_t i = ((size_t)blockIdx.x * 256 + threadIdx.x) * 8;
  float4 a = *(const float4*)(in + i);
  float4 b = *(const float4*)(in + i + 4);
  u16x8 r;
  r[0] = f2bf(a.x); r[1] = f2bf(a.y); r[2] = f2bf(a.z); r[3] = f2bf(a.w);
  r[4] = f2bf(b.x); r[5] = f2bf(b.y); r[6] = f2bf(b.z); r[7] = f2bf(b.w);
  *(u16x8*)(out + i) = r;
}

// ------------------------- layernorm (bf16 out) ---------------------------
__global__ __launch_bounds__(256) void ln_kernel(
    const float* __restrict__ x, const float* __restrict__ g,
    const float* __restrict__ b, u16* __restrict__ y) {
  int row = blockIdx.x, tid = threadIdx.x;
  int lane = tid & 63, w = tid >> 6;
  float4 v = ((const float4*)(x + (size_t)row * DMODEL))[tid];
  float s = v.x + v.y + v.z + v.w;
#pragma unroll
  for (int o = 32; o >= 1; o >>= 1) s += __shfl_xor(s, o);
  __shared__ float red[8];
  if (lane == 0) red[w] = s;
  __syncthreads();
  float mu = (red[0] + red[1] + red[2] + red[3]) * (1.0f / DMODEL);
  float d0 = v.x - mu, d1 = v.y - mu, d2 = v.z - mu, d3 = v.w - mu;
  float s2 = d0*d0 + d1*d1 + d2*d2 + d3*d3;
#pragma unroll
  for (int o = 32; o >= 1; o >>= 1) s2 += __shfl_xor(s2, o);
  if (lane == 0) red[4 + w] = s2;
  __syncthreads();
  float var = (red[4] + red[5] + red[6] + red[7]) * (1.0f / DMODEL);
  float rs = rsqrtf(var + LNEPS);
  float4 gv = ((const float4*)g)[tid];
  float4 bv = ((const float4*)b)[tid];
  u16x4 r;
  r[0] = f2bf(d0 * rs * gv.x + bv.x);
  r[1] = f2bf(d1 * rs * gv.y + bv.y);
  r[2] = f2bf(d2 * rs * gv.z + bv.z);
  r[3] = f2bf(d3 * rs * gv.w + bv.w);
  ((u16x4*)(y + (size_t)row * DMODEL))[tid] = r;
}

// --------------------------- bf16 MFMA GEMM -------------------------------
// C[M,N] = A[M,K] * W[N,K]^T (+bias)(+gelu)(+res). A,W bf16 row-major,
// accum fp32. 128x128 tile, BK=32, 4 waves (2x2 of 64x64), m97 structure.
__device__ __forceinline__ float gelu_f(float v) {
  return 0.5f * v * (1.0f + erff(v * 0.70710678118654752f));
}

template<int ACT, bool BIAS, bool RES, bool OUTBF>
__global__ __launch_bounds__(256) void gemm_mfma(
    const bf16_t* __restrict__ A, const bf16_t* __restrict__ W,
    const float* __restrict__ bias, const float* __restrict__ res,
    void* __restrict__ Cout, int M, int N, int K) {
  __shared__ bf16_t As[128 * 32];
  __shared__ bf16_t Ws[128 * 32];
  const int tid  = threadIdx.x;
  const int lane = tid & 63, w = tid >> 6;
  const int wr = w >> 1, wc = w & 1;
  const int m0 = blockIdx.y * 128, n0 = blockIdx.x * 128;

  const size_t stride = (size_t)K * 2;            // row bytes
  const int srow = lane >> 2;                     // 0..15
  const int scol = (lane & 3) * 16;               // 0,16,32,48

  const char* gA0 = (const char*)A + ((size_t)(m0 + w * 32 + srow)) * stride + scol;
  const char* gA1 = gA0 + 16 * stride;
  const char* gW0 = (const char*)W + ((size_t)(n0 + w * 32 + srow)) * stride + scol;
  const char* gW1 = gW0 + 16 * stride;
  char* lA0 = (char*)As + (w * 32) * 64;
  char* lA1 = lA0 + 16 * 64;
  char* lW0 = (char*)Ws + (w * 32) * 64;
  char* lW1 = lW0 + 16 * 64;

  f32x4 acc[4][4] = {};

  for (int k0 = 0; k0 < K; k0 += 32) {
    gload16(gA0, lA0); gload16(gA1, lA1);
    gload16(gW0, lW0); gload16(gW1, lW1);
    gA0 += 64; gA1 += 64; gW0 += 64; gW1 += 64;
    __syncthreads();                              // vmcnt(0) drained here
    bf16x8 afr[4], bfr[4];
    const int kb = (lane >> 4) * 16;              // 16B k-block offset
    const int rr = lane & 15;
#pragma unroll
    for (int t = 0; t < 4; ++t) {
      afr[t] = *(const bf16x8*)((const char*)As + (wr * 64 + t * 16 + rr) * 64 + kb);
      bfr[t] = *(const bf16x8*)((const char*)Ws + (wc * 64 + t * 16 + rr) * 64 + kb);
    }
#pragma unroll
    for (int mi = 0; mi < 4; ++mi)
#pragma unroll
      for (int ni = 0; ni < 4; ++ni)
        acc[mi][ni] = __builtin_amdgcn_mfma_f32_16x16x32_bf16(
            afr[mi], bfr[ni], acc[mi][ni], 0, 0, 0);
    __syncthreads();                              // reads done before restage
  }

  const int r4 = (lane >> 4) * 4;
  const int cc = lane & 15;
#pragma unroll
  for (int mi = 0; mi < 4; ++mi) {
#pragma unroll
    for (int ni = 0; ni < 4; ++ni) {
      const int col = n0 + wc * 64 + ni * 16 + cc;
      float bv = 0.f;
      if (BIAS) bv = bias[col];
#pragma unroll
      for (int j = 0; j < 4; ++j) {
        const int row = m0 + wr * 64 + mi * 16 + r4 + j;
        float u = acc[mi][ni][j] + bv;
        if (ACT == 1) u = gelu_f(u);
        if (RES) u += res[(size_t)row * N + col];
        if (OUTBF) ((u16*)Cout)[(size_t)row * N + col] = f2bf(u);
        else       ((float*)Cout)[(size_t)row * N + col] = u;
      }
    }
  }
}

// --------------------------- flash attention ------------------------------
// qkv fp32 [B*T, 3*D]; out bf16 [B*T, D]. One (b,h) x 32 q-rows per block.
__global__ __launch_bounds__(256) void attn_kernel(
    const float* __restrict__ qkv, u16* __restrict__ out) {
  int qt = blockIdx.x;
  int bh = blockIdx.y;
  int b = bh >> 4, h = bh & 15;
  int t0 = qt * 32;
  int tid = threadIdx.x;
  int lane = tid & 63, w = tid >> 6;
  __shared__ float kT[HDIM][65];
  __shared__ float vs[64][68];
  const float* qkv_b = qkv + (size_t)b * TSEQ * 3 * DMODEL;

  float q[8], o[8], m[8], l[8];
#pragma unroll
  for (int r = 0; r < 8; ++r) {
    int t = t0 + w * 8 + r;
    q[r] = qkv_b[(size_t)t * (3 * DMODEL) + h * HDIM + lane] * 0.125f;
    o[r] = 0.f; m[r] = -1e30f; l[r] = 0.f;
  }
  int nt = (t0 + 32 + 63) >> 6;
  int sr = tid >> 2;
  int sc = (tid & 3) << 4;

  for (int st = 0; st < nt; ++st) {
    int s0 = st << 6;
    __syncthreads();
    const float* krow = qkv_b + (size_t)(s0 + sr) * (3 * DMODEL) + DMODEL + h * HDIM;
    const float* vrow = krow + DMODEL;
#pragma unroll
    for (int c = 0; c < 16; c += 4) {
      float4 kv = *(const float4*)(krow + sc + c);
      kT[sc + c + 0][sr] = kv.x; kT[sc + c + 1][sr] = kv.y;
      kT[sc + c + 2][sr] = kv.z; kT[sc + c + 3][sr] = kv.w;
      *(float4*)&vs[sr][sc + c] = *(const float4*)(vrow + sc + c);
    }
    __syncthreads();

    float scr[8] = {0, 0, 0, 0, 0, 0, 0, 0};
    for (int d = 0; d < HDIM; ++d) {
      float kd = kT[d][lane];
#pragma unroll
      for (int r = 0; r < 8; ++r) scr[r] += __shfl(q[r], d) * kd;
    }
    if (s0 + 63 > t0) {
#pragma unroll
      for (int r = 0; r < 8; ++r)
        if (s0 + lane > t0 + w * 8 + r) scr[r] = -3e38f;
    }
    float p_[8];
#pragma unroll
    for (int r = 0; r < 8; ++r) {
      float tm = scr[r];
#pragma unroll
      for (int off = 32; off >= 1; off >>= 1) tm = fmaxf(tm, __shfl_xor(tm, off));
      float mn = fmaxf(m[r], tm);
      float p = expf(scr[r] - mn);
      float alpha = expf(m[r] - mn);
      m[r] = mn;
      float ps = p;
#pragma unroll
      for (int off = 32; off >= 1; off >>= 1) ps += __shfl_xor(ps, off);
      l[r] = l[r] * alpha + ps;
      o[r] *= alpha;
      p_[r] = p;
    }
    for (int j = 0; j < 64; ++j) {
      float vv = vs[j][lane];
#pragma unroll
      for (int r = 0; r < 8; ++r) o[r] += __shfl(p_[r], j) * vv;
    }
  }
#pragma unroll
  for (int r = 0; r < 8; ++r) {
    int t = t0 + w * 8 + r;
    out[(size_t)(b * TSEQ + t) * DMODEL + h * HDIM + lane] = f2bf(o[r] / l[r]);
  }
}

// ------------------------------ launcher ----------------------------------
extern "C" void kernel_launch(void* const* d_in, const int* in_sizes, int n_in,
                              void* d_out, int out_size, void* d_ws, size_t ws_size,
                              hipStream_t stream) {
  const int*   ids    = (const int*)d_in[0];
  const float* emb    = (const float*)d_in[1];
  const float* pos    = (const float*)d_in[2];
  const float* ln1_g  = (const float*)d_in[3];
  const float* ln1_b  = (const float*)d_in[4];
  const float* ln2_g  = (const float*)d_in[5];
  const float* ln2_b  = (const float*)d_in[6];
  const float* qkv_w  = (const float*)d_in[7];
  const float* out_w  = (const float*)d_in[8];
  const float* mlp_w1 = (const float*)d_in[9];
  const float* mlp_b1 = (const float*)d_in[10];
  const float* mlp_w2 = (const float*)d_in[11];
  const float* mlp_b2 = (const float*)d_in[12];
  const float* lnf_g  = (const float*)d_in[13];
  const float* lnf_b  = (const float*)d_in[14];
  float* outp = (float*)d_out;

  const int M = BATCH * TSEQ;                         // 4096
  char* p = (char*)d_ws;
  float* x    = (float*)p;  p += (size_t)M * DMODEL * 4;       // 16.78 MB
  u16*   yb   = (u16*)p;    p += (size_t)M * DMODEL * 2;       //  8.39 MB
  char*  qkv_region = p;
  float* qkvb = (float*)p;  p += (size_t)M * 3 * DMODEL * 4;   // 50.33 MB
  u16*   mid  = (u16*)p;    p += (size_t)M * DFFN * 2;         // 33.55 MB
  u16*   wq   = (u16*)p;    p += (size_t)3 * DMODEL * DMODEL * 2;
  u16*   wo   = (u16*)p;    p += (size_t)DMODEL * DMODEL * 2;
  u16*   w1   = (u16*)p;    p += (size_t)DFFN * DMODEL * 2;
  u16*   w2   = (u16*)p;    p += (size_t)DMODEL * DFFN * 2;    // total ~134 MB
  u16*   embb = (u16*)qkv_region;                              // reuse 65.5 MB

  embed_kernel<<<M, 256, 0, stream>>>(ids, emb, pos, x);

  for (int l = 0; l < NLAYER; ++l) {
    cvt_bf16_kernel<<<1536, 256, 0, stream>>>(qkv_w  + (size_t)l * 3 * DMODEL * DMODEL, wq);
    cvt_bf16_kernel<<< 512, 256, 0, stream>>>(out_w  + (size_t)l * DMODEL * DMODEL,     wo);
    cvt_bf16_kernel<<<2048, 256, 0, stream>>>(mlp_w1 + (size_t)l * DFFN * DMODEL,       w1);
    cvt_bf16_kernel<<<2048, 256, 0, stream>>>(mlp_w2 + (size_t)l * DMODEL * DFFN,       w2);

    ln_kernel<<<M, 256, 0, stream>>>(x, ln1_g + l * DMODEL, ln1_b + l * DMODEL, yb);
    gemm_mfma<0, false, false, false><<<dim3(3 * DMODEL / 128, M / 128), 256, 0, stream>>>(
        (const bf16_t*)yb, (const bf16_t*)wq, nullptr, nullptr, qkvb, M, 3 * DMODEL, DMODEL);
    attn_kernel<<<dim3(TSEQ / 32, BATCH * NHEAD), 256, 0, stream>>>(qkvb, yb);
    gemm_mfma<0, false, true, false><<<dim3(DMODEL / 128, M / 128), 256, 0, stream>>>(
        (const bf16_t*)yb, (const bf16_t*)wo, nullptr, x, x, M, DMODEL, DMODEL);
    ln_kernel<<<M, 256, 0, stream>>>(x, ln2_g + l * DMODEL, ln2_b + l * DMODEL, yb);
    gemm_mfma<1, true, false, true><<<dim3(DFFN / 128, M / 128), 256, 0, stream>>>(
        (const bf16_t*)yb, (const bf16_t*)w1, mlp_b1 + (size_t)l * DFFN, nullptr, mid,
        M, DFFN, DMODEL);
    gemm_mfma<0, true, true, false><<<dim3(DMODEL / 128, M / 128), 256, 0, stream>>>(
        (const bf16_t*)mid, (const bf16_t*)w2, mlp_b2 + (size_t)l * DMODEL, x, x,
        M, DMODEL, DFFN);
  }

  ln_kernel<<<M, 256, 0, stream>>>(x, lnf_g, lnf_b, yb);
  cvt_bf16_kernel<<<16000, 256, 0, stream>>>(emb, embb);
  gemm_mfma<0, false, false, false><<<dim3(NVOCAB / 128, M / 128), 256, 0, stream>>>(
      (const bf16_t*)yb, (const bf16_t*)embb, nullptr, nullptr, outp, M, NVOCAB, DMODEL);
}

// Round 3
// 2966.824 us; speedup vs baseline: 9.5320x; 6.1012x over previous
//
#include <hip/hip_runtime.h>
#include <math.h>

#define TSEQ   2048
#define BATCH  2
#define DMODEL 1024
#define NLAYER 6
#define NHEAD  16
#define HDIM   64
#define DFFN   4096
#define NVOCAB 32000
#define LNEPS  1e-5f

typedef __bf16 bf16_t;
typedef bf16_t bf16x8 __attribute__((ext_vector_type(8)));
typedef float  f32x4  __attribute__((ext_vector_type(4)));
typedef unsigned short u16;
typedef u16 u16x4 __attribute__((ext_vector_type(4)));
typedef u16 u16x8 __attribute__((ext_vector_type(8)));

__device__ __forceinline__ u16 f2bf(float f) {   // RNE fp32 -> bf16 bits
  unsigned u = __float_as_uint(f);
  return (u16)((u + 0x7fffu + ((u >> 16) & 1u)) >> 16);
}

__device__ __forceinline__ void gload16(const void* g, void* l) {
  __builtin_amdgcn_global_load_lds(
      (const __attribute__((address_space(1))) unsigned int*)g,
      (__attribute__((address_space(3))) unsigned int*)l, 16, 0, 0);
}

// ----------------------------- embedding ---------------------------------
__global__ __launch_bounds__(256) void embed_kernel(
    const int* __restrict__ ids, const float* __restrict__ emb,
    const float* __restrict__ pos, float* __restrict__ x) {
  int bt  = blockIdx.x;
  int t   = bt & (TSEQ - 1);
  int id  = ids[bt];
  int tid = threadIdx.x;
  float4 e = ((const float4*)(emb + (size_t)id * DMODEL))[tid];
  float4 p = ((const float4*)(pos + (size_t)t  * DMODEL))[tid];
  float4 r;
  r.x = e.x + p.x; r.y = e.y + p.y; r.z = e.z + p.z; r.w = e.w + p.w;
  ((float4*)(x + (size_t)bt * DMODEL))[tid] = r;
}

// ------------------------- fp32 -> bf16 convert ---------------------------
__global__ __launch_bounds__(256) void cvt_bf16_kernel(
    const float* __restrict__ in, u16* __restrict__ out) {
  size_t i = ((size_t)blockIdx.x * 256 + threadIdx.x) * 8;
  float4 a = *(const float4*)(in + i);
  float4 b = *(const float4*)(in + i + 4);
  u16x8 r;
  r[0] = f2bf(a.x); r[1] = f2bf(a.y); r[2] = f2bf(a.z); r[3] = f2bf(a.w);
  r[4] = f2bf(b.x); r[5] = f2bf(b.y); r[6] = f2bf(b.z); r[7] = f2bf(b.w);
  *(u16x8*)(out + i) = r;
}

// ------------------------- layernorm (bf16 out) ---------------------------
__global__ __launch_bounds__(256) void ln_kernel(
    const float* __restrict__ x, const float* __restrict__ g,
    const float* __restrict__ b, u16* __restrict__ y) {
  int row = blockIdx.x, tid = threadIdx.x;
  int lane = tid & 63, w = tid >> 6;
  float4 v = ((const float4*)(x + (size_t)row * DMODEL))[tid];
  float s = v.x + v.y + v.z + v.w;
#pragma unroll
  for (int o = 32; o >= 1; o >>= 1) s += __shfl_xor(s, o);
  __shared__ float red[8];
  if (lane == 0) red[w] = s;
  __syncthreads();
  float mu = (red[0] + red[1] + red[2] + red[3]) * (1.0f / DMODEL);
  float d0 = v.x - mu, d1 = v.y - mu, d2 = v.z - mu, d3 = v.w - mu;
  float s2 = d0*d0 + d1*d1 + d2*d2 + d3*d3;
#pragma unroll
  for (int o = 32; o >= 1; o >>= 1) s2 += __shfl_xor(s2, o);
  if (lane == 0) red[4 + w] = s2;
  __syncthreads();
  float var = (red[4] + red[5] + red[6] + red[7]) * (1.0f / DMODEL);
  float rs = rsqrtf(var + LNEPS);
  float4 gv = ((const float4*)g)[tid];
  float4 bv = ((const float4*)b)[tid];
  u16x4 r;
  r[0] = f2bf(d0 * rs * gv.x + bv.x);
  r[1] = f2bf(d1 * rs * gv.y + bv.y);
  r[2] = f2bf(d2 * rs * gv.z + bv.z);
  r[3] = f2bf(d3 * rs * gv.w + bv.w);
  ((u16x4*)(y + (size_t)row * DMODEL))[tid] = r;
}

// --------------------------- bf16 MFMA GEMM -------------------------------
__device__ __forceinline__ float gelu_f(float v) {
  return 0.5f * v * (1.0f + erff(v * 0.70710678118654752f));
}

template<int ACT, bool BIAS, bool RES, bool OUTBF>
__global__ __launch_bounds__(256) void gemm_mfma(
    const bf16_t* __restrict__ A, const bf16_t* __restrict__ W,
    const float* __restrict__ bias, const float* __restrict__ res,
    void* __restrict__ Cout, int M, int N, int K) {
  __shared__ bf16_t As[128 * 32];
  __shared__ bf16_t Ws[128 * 32];
  const int tid  = threadIdx.x;
  const int lane = tid & 63, w = tid >> 6;
  const int wr = w >> 1, wc = w & 1;
  const int m0 = blockIdx.y * 128, n0 = blockIdx.x * 128;

  const size_t stride = (size_t)K * 2;            // row bytes
  const int srow = lane >> 2;                     // 0..15
  const int scol = (lane & 3) * 16;               // 0,16,32,48

  const char* gA0 = (const char*)A + ((size_t)(m0 + w * 32 + srow)) * stride + scol;
  const char* gA1 = gA0 + 16 * stride;
  const char* gW0 = (const char*)W + ((size_t)(n0 + w * 32 + srow)) * stride + scol;
  const char* gW1 = gW0 + 16 * stride;
  char* lA0 = (char*)As + (w * 32) * 64;
  char* lA1 = lA0 + 16 * 64;
  char* lW0 = (char*)Ws + (w * 32) * 64;
  char* lW1 = lW0 + 16 * 64;

  f32x4 acc[4][4] = {};

  for (int k0 = 0; k0 < K; k0 += 32) {
    gload16(gA0, lA0); gload16(gA1, lA1);
    gload16(gW0, lW0); gload16(gW1, lW1);
    gA0 += 64; gA1 += 64; gW0 += 64; gW1 += 64;
    __syncthreads();
    bf16x8 afr[4], bfr[4];
    const int kb = (lane >> 4) * 16;
    const int rr = lane & 15;
#pragma unroll
    for (int t = 0; t < 4; ++t) {
      afr[t] = *(const bf16x8*)((const char*)As + (wr * 64 + t * 16 + rr) * 64 + kb);
      bfr[t] = *(const bf16x8*)((const char*)Ws + (wc * 64 + t * 16 + rr) * 64 + kb);
    }
#pragma unroll
    for (int mi = 0; mi < 4; ++mi)
#pragma unroll
      for (int ni = 0; ni < 4; ++ni)
        acc[mi][ni] = __builtin_amdgcn_mfma_f32_16x16x32_bf16(
            afr[mi], bfr[ni], acc[mi][ni], 0, 0, 0);
    __syncthreads();
  }

  const int r4 = (lane >> 4) * 4;
  const int cc = lane & 15;
#pragma unroll
  for (int mi = 0; mi < 4; ++mi) {
#pragma unroll
    for (int ni = 0; ni < 4; ++ni) {
      const int col = n0 + wc * 64 + ni * 16 + cc;
      float bv = 0.f;
      if (BIAS) bv = bias[col];
#pragma unroll
      for (int j = 0; j < 4; ++j) {
        const int row = m0 + wr * 64 + mi * 16 + r4 + j;
        float u = acc[mi][ni][j] + bv;
        if (ACT == 1) u = gelu_f(u);
        if (RES) u += res[(size_t)row * N + col];
        if (OUTBF) ((u16*)Cout)[(size_t)row * N + col] = f2bf(u);
        else       ((float*)Cout)[(size_t)row * N + col] = u;
      }
    }
  }
}

// ----------------------- MFMA flash attention -----------------------------
// qkv bf16 [B*T, 3*D]; out bf16 [B*T, D]. Block: one (b,h) x 64 q-rows,
// 4 waves x 16 rows. Per 64-key tile: K row-major [64][72], V transposed
// [d][key] stride 72, P per-wave [16][72]. fp32 online softmax.
__global__ __launch_bounds__(256) void attn_mfma_kernel(
    const u16* __restrict__ qkv, u16* __restrict__ out) {
  const int qb0 = blockIdx.x * 64;
  const int bh  = blockIdx.y;
  const int b = bh >> 4, h = bh & 15;
  const int tid = threadIdx.x;
  const int lane = tid & 63, w = tid >> 6;

  __shared__ u16 Ks[64][72];
  __shared__ u16 Vt[64][72];
  __shared__ u16 Ps[4][16][72];

  const size_t rowstr = 3 * DMODEL;
  const u16* base = qkv + (size_t)b * TSEQ * rowstr;

  const int fr = lane & 15;          // frag row/col
  const int fk = (lane >> 4) * 8;    // frag k offset
  const int qminw = qb0 + w * 16;
  const int qrow = qminw + fr;

  bf16x8 qf0 = *(const bf16x8*)(base + (size_t)qrow * rowstr + h * HDIM + fk);
  bf16x8 qf1 = *(const bf16x8*)(base + (size_t)qrow * rowstr + h * HDIM + fk + 32);

  f32x4 o[4] = {};
  float m[4] = {-1e30f, -1e30f, -1e30f, -1e30f};
  float l[4] = {0.f, 0.f, 0.f, 0.f};

  const int sr = tid >> 2;           // key 0..63
  const int sc = (tid & 3) * 16;     // dim 0,16,32,48

  for (int s0 = 0; s0 < qb0 + 64; s0 += 64) {
    __syncthreads();                 // prev-tile LDS reads done
    const u16* krow = base + (size_t)(s0 + sr) * rowstr + DMODEL + h * HDIM + sc;
    const u16* vrow = krow + DMODEL;
    u16x8 k0 = *(const u16x8*)krow;
    u16x8 k1 = *(const u16x8*)(krow + 8);
    u16x8 v0 = *(const u16x8*)vrow;
    u16x8 v1 = *(const u16x8*)(vrow + 8);
    *(u16x8*)&Ks[sr][sc]     = k0;
    *(u16x8*)&Ks[sr][sc + 8] = k1;
#pragma unroll
    for (int i = 0; i < 8; ++i) {
      Vt[sc + i][sr]     = v0[i];
      Vt[sc + 8 + i][sr] = v1[i];
    }
    __syncthreads();

    // QK^T: S[q][key], q = fr rows of this wave, keys = 4 subtiles of 16
    f32x4 s[4] = {};
#pragma unroll
    for (int ni = 0; ni < 4; ++ni) {
      bf16x8 kf0 = *(const bf16x8*)&Ks[ni * 16 + fr][fk];
      bf16x8 kf1 = *(const bf16x8*)&Ks[ni * 16 + fr][fk + 32];
      s[ni] = __builtin_amdgcn_mfma_f32_16x16x32_bf16(qf0, kf0, s[ni], 0, 0, 0);
      s[ni] = __builtin_amdgcn_mfma_f32_16x16x32_bf16(qf1, kf1, s[ni], 0, 0, 0);
    }
#pragma unroll
    for (int ni = 0; ni < 4; ++ni)
#pragma unroll
      for (int j = 0; j < 4; ++j) s[ni][j] *= 0.125f;

    if (s0 + 63 > qminw) {           // diagonal region: causal mask
      const int key0 = s0 + fr;
      const int q0_  = qminw + (lane >> 4) * 4;
#pragma unroll
      for (int ni = 0; ni < 4; ++ni)
#pragma unroll
        for (int j = 0; j < 4; ++j)
          if (key0 + ni * 16 > q0_ + j) s[ni][j] = -3e38f;
    }

    // online softmax (rows split across 16-lane groups)
#pragma unroll
    for (int j = 0; j < 4; ++j) {
      float tm = fmaxf(fmaxf(s[0][j], s[1][j]), fmaxf(s[2][j], s[3][j]));
      tm = fmaxf(tm, __shfl_xor(tm, 1));
      tm = fmaxf(tm, __shfl_xor(tm, 2));
      tm = fmaxf(tm, __shfl_xor(tm, 4));
      tm = fmaxf(tm, __shfl_xor(tm, 8));
      float mn = fmaxf(m[j], tm);
      float al = expf(m[j] - mn);
      m[j] = mn;
      float ps = 0.f;
#pragma unroll
      for (int ni = 0; ni < 4; ++ni) {
        float pv = expf(s[ni][j] - mn);
        s[ni][j] = pv;
        ps += pv;
      }
      ps += __shfl_xor(ps, 1);
      ps += __shfl_xor(ps, 2);
      ps += __shfl_xor(ps, 4);
      ps += __shfl_xor(ps, 8);
      l[j] = l[j] * al + ps;
#pragma unroll
      for (int ni = 0; ni < 4; ++ni) o[ni][j] *= al;
    }

    // P -> LDS (bf16), wave-private
#pragma unroll
    for (int ni = 0; ni < 4; ++ni)
#pragma unroll
      for (int j = 0; j < 4; ++j)
        Ps[w][(lane >> 4) * 4 + j][ni * 16 + fr] = f2bf(s[ni][j]);
    asm volatile("s_waitcnt lgkmcnt(0)" ::: "memory");

    // PV: O[q][d] += P[q][key] * V[key][d]
    bf16x8 pf0 = *(const bf16x8*)&Ps[w][fr][fk];
    bf16x8 pf1 = *(const bf16x8*)&Ps[w][fr][fk + 32];
#pragma unroll
    for (int ni = 0; ni < 4; ++ni) {
      bf16x8 vf0 = *(const bf16x8*)&Vt[ni * 16 + fr][fk];
      bf16x8 vf1 = *(const bf16x8*)&Vt[ni * 16 + fr][fk + 32];
      o[ni] = __builtin_amdgcn_mfma_f32_16x16x32_bf16(pf0, vf0, o[ni], 0, 0, 0);
      o[ni] = __builtin_amdgcn_mfma_f32_16x16x32_bf16(pf1, vf1, o[ni], 0, 0, 0);
    }
  }

#pragma unroll
  for (int j = 0; j < 4; ++j) {
    float inv = 1.0f / l[j];
    int q = qminw + (lane >> 4) * 4 + j;
    u16* op = out + ((size_t)(b * TSEQ) + q) * DMODEL + h * HDIM + fr;
#pragma unroll
    for (int ni = 0; ni < 4; ++ni)
      op[ni * 16] = f2bf(o[ni][j] * inv);
  }
}

// ------------------------------ launcher ----------------------------------
extern "C" void kernel_launch(void* const* d_in, const int* in_sizes, int n_in,
                              void* d_out, int out_size, void* d_ws, size_t ws_size,
                              hipStream_t stream) {
  const int*   ids    = (const int*)d_in[0];
  const float* emb    = (const float*)d_in[1];
  const float* pos    = (const float*)d_in[2];
  const float* ln1_g  = (const float*)d_in[3];
  const float* ln1_b  = (const float*)d_in[4];
  const float* ln2_g  = (const float*)d_in[5];
  const float* ln2_b  = (const float*)d_in[6];
  const float* qkv_w  = (const float*)d_in[7];
  const float* out_w  = (const float*)d_in[8];
  const float* mlp_w1 = (const float*)d_in[9];
  const float* mlp_b1 = (const float*)d_in[10];
  const float* mlp_w2 = (const float*)d_in[11];
  const float* mlp_b2 = (const float*)d_in[12];
  const float* lnf_g  = (const float*)d_in[13];
  const float* lnf_b  = (const float*)d_in[14];
  float* outp = (float*)d_out;

  const int M = BATCH * TSEQ;                         // 4096
  char* p = (char*)d_ws;
  float* x    = (float*)p;  p += (size_t)M * DMODEL * 4;       // 16.78 MB
  u16*   yb   = (u16*)p;    p += (size_t)M * DMODEL * 2;       //  8.39 MB
  u16*   qkvb = (u16*)p;    p += (size_t)M * 3 * DMODEL * 2;   // 25.17 MB
  u16*   mid  = (u16*)p;    p += (size_t)M * DFFN * 2;         // 33.55 MB
  u16*   wq   = (u16*)p;    p += (size_t)3 * DMODEL * DMODEL * 2;
  u16*   wo   = (u16*)p;    p += (size_t)DMODEL * DMODEL * 2;
  u16*   w1   = (u16*)p;    p += (size_t)DFFN * DMODEL * 2;
  u16*   w2   = (u16*)p;    p += (size_t)DMODEL * DFFN * 2;    // ~109 MB total
  u16*   embb = qkvb;  // final stage: reuse qkvb+mid+wq (all dead), 65.5 MB

  embed_kernel<<<M, 256, 0, stream>>>(ids, emb, pos, x);

  for (int l = 0; l < NLAYER; ++l) {
    cvt_bf16_kernel<<<1536, 256, 0, stream>>>(qkv_w  + (size_t)l * 3 * DMODEL * DMODEL, wq);
    cvt_bf16_kernel<<< 512, 256, 0, stream>>>(out_w  + (size_t)l * DMODEL * DMODEL,     wo);
    cvt_bf16_kernel<<<2048, 256, 0, stream>>>(mlp_w1 + (size_t)l * DFFN * DMODEL,       w1);
    cvt_bf16_kernel<<<2048, 256, 0, stream>>>(mlp_w2 + (size_t)l * DMODEL * DFFN,       w2);

    ln_kernel<<<M, 256, 0, stream>>>(x, ln1_g + l * DMODEL, ln1_b + l * DMODEL, yb);
    gemm_mfma<0, false, false, true><<<dim3(3 * DMODEL / 128, M / 128), 256, 0, stream>>>(
        (const bf16_t*)yb, (const bf16_t*)wq, nullptr, nullptr, qkvb, M, 3 * DMODEL, DMODEL);
    attn_mfma_kernel<<<dim3(TSEQ / 64, BATCH * NHEAD), 256, 0, stream>>>(qkvb, yb);
    gemm_mfma<0, false, true, false><<<dim3(DMODEL / 128, M / 128), 256, 0, stream>>>(
        (const bf16_t*)yb, (const bf16_t*)wo, nullptr, x, x, M, DMODEL, DMODEL);
    ln_kernel<<<M, 256, 0, stream>>>(x, ln2_g + l * DMODEL, ln2_b + l * DMODEL, yb);
    gemm_mfma<1, true, false, true><<<dim3(DFFN / 128, M / 128), 256, 0, stream>>>(
        (const bf16_t*)yb, (const bf16_t*)w1, mlp_b1 + (size_t)l * DFFN, nullptr, mid,
        M, DFFN, DMODEL);
    gemm_mfma<0, true, true, false><<<dim3(DMODEL / 128, M / 128), 256, 0, stream>>>(
        (const bf16_t*)mid, (const bf16_t*)w2, mlp_b2 + (size_t)l * DMODEL, x, x,
        M, DMODEL, DFFN);
  }

  ln_kernel<<<M, 256, 0, stream>>>(x, lnf_g, lnf_b, yb);
  cvt_bf16_kernel<<<16000, 256, 0, stream>>>(emb, embb);
  gemm_mfma<0, false, false, false><<<dim3(NVOCAB / 128, M / 128), 256, 0, stream>>>(
      (const bf16_t*)yb, (const bf16_t*)embb, nullptr, nullptr, outp, M, NVOCAB, DMODEL);
}

// Round 4
// 2826.986 us; speedup vs baseline: 10.0035x; 1.0495x over previous
//
#include <hip/hip_runtime.h>
#include <math.h>

#define TSEQ   2048
#define BATCH  2
#define DMODEL 1024
#define NLAYER 6
#define NHEAD  16
#define HDIM   64
#define DFFN   4096
#define NVOCAB 32000
#define LNEPS  1e-5f

typedef __bf16 bf16_t;
typedef bf16_t bf16x8 __attribute__((ext_vector_type(8)));
typedef float  f32x4  __attribute__((ext_vector_type(4)));
typedef unsigned short u16;
typedef u16 u16x4 __attribute__((ext_vector_type(4)));
typedef u16 u16x8 __attribute__((ext_vector_type(8)));

__device__ __forceinline__ u16 f2bf(float f) {   // RNE fp32 -> bf16 bits
  unsigned u = __float_as_uint(f);
  return (u16)((u + 0x7fffu + ((u >> 16) & 1u)) >> 16);
}

__device__ __forceinline__ void gload16(const void* g, void* l) {
  __builtin_amdgcn_global_load_lds(
      (const __attribute__((address_space(1))) unsigned int*)g,
      (__attribute__((address_space(3))) unsigned int*)l, 16, 0, 0);
}

// ----------------------------- embedding ---------------------------------
__global__ __launch_bounds__(256) void embed_kernel(
    const int* __restrict__ ids, const float* __restrict__ emb,
    const float* __restrict__ pos, float* __restrict__ x) {
  int bt  = blockIdx.x;
  int t   = bt & (TSEQ - 1);
  int id  = ids[bt];
  int tid = threadIdx.x;
  float4 e = ((const float4*)(emb + (size_t)id * DMODEL))[tid];
  float4 p = ((const float4*)(pos + (size_t)t  * DMODEL))[tid];
  float4 r;
  r.x = e.x + p.x; r.y = e.y + p.y; r.z = e.z + p.z; r.w = e.w + p.w;
  ((float4*)(x + (size_t)bt * DMODEL))[tid] = r;
}

// ------------------------- fp32 -> bf16 convert ---------------------------
__global__ __launch_bounds__(256) void cvt_bf16_kernel(
    const float* __restrict__ in, u16* __restrict__ out) {
  size_t i = ((size_t)blockIdx.x * 256 + threadIdx.x) * 8;
  float4 a = *(const float4*)(in + i);
  float4 b = *(const float4*)(in + i + 4);
  u16x8 r;
  r[0] = f2bf(a.x); r[1] = f2bf(a.y); r[2] = f2bf(a.z); r[3] = f2bf(a.w);
  r[4] = f2bf(b.x); r[5] = f2bf(b.y); r[6] = f2bf(b.z); r[7] = f2bf(b.w);
  *(u16x8*)(out + i) = r;
}

// ------------------------- layernorm (bf16 out) ---------------------------
__global__ __launch_bounds__(256) void ln_kernel(
    const float* __restrict__ x, const float* __restrict__ g,
    const float* __restrict__ b, u16* __restrict__ y) {
  int row = blockIdx.x, tid = threadIdx.x;
  int lane = tid & 63, w = tid >> 6;
  float4 v = ((const float4*)(x + (size_t)row * DMODEL))[tid];
  float s = v.x + v.y + v.z + v.w;
#pragma unroll
  for (int o = 32; o >= 1; o >>= 1) s += __shfl_xor(s, o);
  __shared__ float red[8];
  if (lane == 0) red[w] = s;
  __syncthreads();
  float mu = (red[0] + red[1] + red[2] + red[3]) * (1.0f / DMODEL);
  float d0 = v.x - mu, d1 = v.y - mu, d2 = v.z - mu, d3 = v.w - mu;
  float s2 = d0*d0 + d1*d1 + d2*d2 + d3*d3;
#pragma unroll
  for (int o = 32; o >= 1; o >>= 1) s2 += __shfl_xor(s2, o);
  if (lane == 0) red[4 + w] = s2;
  __syncthreads();
  float var = (red[4] + red[5] + red[6] + red[7]) * (1.0f / DMODEL);
  float rs = rsqrtf(var + LNEPS);
  float4 gv = ((const float4*)g)[tid];
  float4 bv = ((const float4*)b)[tid];
  u16x4 r;
  r[0] = f2bf(d0 * rs * gv.x + bv.x);
  r[1] = f2bf(d1 * rs * gv.y + bv.y);
  r[2] = f2bf(d2 * rs * gv.z + bv.z);
  r[3] = f2bf(d3 * rs * gv.w + bv.w);
  ((u16x4*)(y + (size_t)row * DMODEL))[tid] = r;
}

// --------------------------- bf16 MFMA GEMM -------------------------------
__device__ __forceinline__ float gelu_f(float v) {
  return 0.5f * v * (1.0f + erff(v * 0.70710678118654752f));
}

// C[M,N] = A[M,K]*W[N,K]^T (+bias)(+gelu)(+res). 128x128 tile, BK=32.
// XCD-aware swizzle, column-major within chunk: each XCD walks one N-panel
// across all 32 M-tiles -> W-tile stays in that XCD's L2. gridDim.y==32.
template<int ACT, bool BIAS, bool RES, bool OUTBF>
__global__ __launch_bounds__(256) void gemm_mfma(
    const bf16_t* __restrict__ A, const bf16_t* __restrict__ W,
    const float* __restrict__ bias, const float* __restrict__ res,
    void* __restrict__ Cout, int M, int N, int K) {
  __shared__ bf16_t As[128 * 32];
  __shared__ bf16_t Ws[128 * 32];
  const int tid  = threadIdx.x;
  const int lane = tid & 63, w = tid >> 6;
  const int wr = w >> 1, wc = w & 1;

  const int gx  = gridDim.x;
  const int bid = blockIdx.y * gx + blockIdx.x;
  const int cpx = (gx * 32) >> 3;                 // nwg/8 (nwg%8==0)
  const int swz = (bid & 7) * cpx + (bid >> 3);
  const int m0 = (swz & 31) * 128;                // M-tile fast within chunk
  const int n0 = (swz >> 5) * 128;

  const size_t stride = (size_t)K * 2;            // row bytes
  const int srow = lane >> 2;                     // 0..15
  const int scol = (lane & 3) * 16;               // 0,16,32,48

  const char* gA0 = (const char*)A + ((size_t)(m0 + w * 32 + srow)) * stride + scol;
  const char* gA1 = gA0 + 16 * stride;
  const char* gW0 = (const char*)W + ((size_t)(n0 + w * 32 + srow)) * stride + scol;
  const char* gW1 = gW0 + 16 * stride;
  char* lA0 = (char*)As + (w * 32) * 64;
  char* lA1 = lA0 + 16 * 64;
  char* lW0 = (char*)Ws + (w * 32) * 64;
  char* lW1 = lW0 + 16 * 64;

  f32x4 acc[4][4] = {};

  for (int k0 = 0; k0 < K; k0 += 32) {
    gload16(gA0, lA0); gload16(gA1, lA1);
    gload16(gW0, lW0); gload16(gW1, lW1);
    gA0 += 64; gA1 += 64; gW0 += 64; gW1 += 64;
    __syncthreads();
    bf16x8 afr[4], bfr[4];
    const int kb = (lane >> 4) * 16;
    const int rr = lane & 15;
#pragma unroll
    for (int t = 0; t < 4; ++t) {
      afr[t] = *(const bf16x8*)((const char*)As + (wr * 64 + t * 16 + rr) * 64 + kb);
      bfr[t] = *(const bf16x8*)((const char*)Ws + (wc * 64 + t * 16 + rr) * 64 + kb);
    }
#pragma unroll
    for (int mi = 0; mi < 4; ++mi)
#pragma unroll
      for (int ni = 0; ni < 4; ++ni)
        acc[mi][ni] = __builtin_amdgcn_mfma_f32_16x16x32_bf16(
            afr[mi], bfr[ni], acc[mi][ni], 0, 0, 0);
    __syncthreads();
  }

  const int r4 = (lane >> 4) * 4;
  const int cc = lane & 15;
#pragma unroll
  for (int mi = 0; mi < 4; ++mi) {
#pragma unroll
    for (int ni = 0; ni < 4; ++ni) {
      const int col = n0 + wc * 64 + ni * 16 + cc;
      float bv = 0.f;
      if (BIAS) bv = bias[col];
#pragma unroll
      for (int j = 0; j < 4; ++j) {
        const int row = m0 + wr * 64 + mi * 16 + r4 + j;
        float u = acc[mi][ni][j] + bv;
        if (ACT == 1) u = gelu_f(u);
        if (RES) u += res[(size_t)row * N + col];
        if (OUTBF) ((u16*)Cout)[(size_t)row * N + col] = f2bf(u);
        else       ((float*)Cout)[(size_t)row * N + col] = u;
      }
    }
  }
}

// ----------------------- MFMA flash attention -----------------------------
// qkv bf16 [B*T, 3*D]; out bf16 [B*T, D]. Block: one (b,h) x 64 q-rows,
// 4 waves x 16 rows. Async prefetch: next tile's K/V global loads issue
// right after the publish barrier, written to LDS next iteration.
__global__ __launch_bounds__(256) void attn_mfma_kernel(
    const u16* __restrict__ qkv, u16* __restrict__ out) {
  const int qb0 = blockIdx.x * 64;
  const int bh  = blockIdx.y;
  const int b = bh >> 4, h = bh & 15;
  const int tid = threadIdx.x;
  const int lane = tid & 63, w = tid >> 6;

  __shared__ u16 Ks[64][72];
  __shared__ u16 Vt[64][72];
  __shared__ u16 Ps[4][16][72];

  const size_t rowstr = 3 * DMODEL;
  const u16* base = qkv + (size_t)b * TSEQ * rowstr;

  const int fr = lane & 15;          // frag row/col
  const int fk = (lane >> 4) * 8;    // frag k offset
  const int qminw = qb0 + w * 16;
  const int qrow = qminw + fr;

  // Q frags pre-scaled by HD^-0.5 = 0.125 (fp32 round-trip, once per block)
  u16x8 q0r = *(const u16x8*)(base + (size_t)qrow * rowstr + h * HDIM + fk);
  u16x8 q1r = *(const u16x8*)(base + (size_t)qrow * rowstr + h * HDIM + fk + 32);
  bf16x8 qf0, qf1;
#pragma unroll
  for (int i = 0; i < 8; ++i) {
    ((u16*)&qf0)[i] = f2bf(__uint_as_float((unsigned)q0r[i] << 16) * 0.125f);
    ((u16*)&qf1)[i] = f2bf(__uint_as_float((unsigned)q1r[i] << 16) * 0.125f);
  }

  f32x4 o[4] = {};
  float m[4] = {-1e30f, -1e30f, -1e30f, -1e30f};
  float l[4] = {0.f, 0.f, 0.f, 0.f};

  // staging split: K by (row, 32B-col); V by (key-pair, 8-dim group)
  const int skr = tid >> 2;            // 0..63
  const int skc = (tid & 3) * 16;      // 0,16,32,48
  const int vk0 = (tid & 31) * 2;      // even key
  const int vd0 = (tid >> 5) * 8;      // dim group

  u16x8 kA, kB, vA, vB;
  {
    const u16* kr = base + (size_t)skr * rowstr + DMODEL + h * HDIM + skc;
    kA = *(const u16x8*)kr; kB = *(const u16x8*)(kr + 8);
    const u16* vr = base + (size_t)vk0 * rowstr + 2 * DMODEL + h * HDIM + vd0;
    vA = *(const u16x8*)vr; vB = *(const u16x8*)(vr + rowstr);
  }

  for (int s0 = 0; s0 <= qb0; s0 += 64) {
    __syncthreads();                   // prev-tile LDS reads done
    *(u16x8*)&Ks[skr][skc]     = kA;
    *(u16x8*)&Ks[skr][skc + 8] = kB;
#pragma unroll
    for (int i = 0; i < 8; ++i) {      // pair-packed transpose: conflict-free
      unsigned pk = (unsigned)vA[i] | ((unsigned)vB[i] << 16);
      *(unsigned*)&Vt[vd0 + i][vk0] = pk;
    }
    __syncthreads();

    if (s0 + 64 <= qb0) {              // async prefetch next tile
      const u16* kr = base + (size_t)(s0 + 64 + skr) * rowstr + DMODEL + h * HDIM + skc;
      kA = *(const u16x8*)kr; kB = *(const u16x8*)(kr + 8);
      const u16* vr = base + (size_t)(s0 + 64 + vk0) * rowstr + 2 * DMODEL + h * HDIM + vd0;
      vA = *(const u16x8*)vr; vB = *(const u16x8*)(vr + rowstr);
    }

    // QK^T
    f32x4 s[4] = {};
    __builtin_amdgcn_s_setprio(1);
#pragma unroll
    for (int ni = 0; ni < 4; ++ni) {
      bf16x8 kf0 = *(const bf16x8*)&Ks[ni * 16 + fr][fk];
      bf16x8 kf1 = *(const bf16x8*)&Ks[ni * 16 + fr][fk + 32];
      s[ni] = __builtin_amdgcn_mfma_f32_16x16x32_bf16(qf0, kf0, s[ni], 0, 0, 0);
      s[ni] = __builtin_amdgcn_mfma_f32_16x16x32_bf16(qf1, kf1, s[ni], 0, 0, 0);
    }
    __builtin_amdgcn_s_setprio(0);

    if (s0 + 63 > qminw) {             // causal mask (diagonal region)
      const int key0 = s0 + fr;
      const int q0_  = qminw + (lane >> 4) * 4;
#pragma unroll
      for (int ni = 0; ni < 4; ++ni)
#pragma unroll
        for (int j = 0; j < 4; ++j)
          if (key0 + ni * 16 > q0_ + j) s[ni][j] = -3e38f;
    }

    // online softmax (rows split across 16-lane groups)
#pragma unroll
    for (int j = 0; j < 4; ++j) {
      float tm = fmaxf(fmaxf(s[0][j], s[1][j]), fmaxf(s[2][j], s[3][j]));
      tm = fmaxf(tm, __shfl_xor(tm, 1));
      tm = fmaxf(tm, __shfl_xor(tm, 2));
      tm = fmaxf(tm, __shfl_xor(tm, 4));
      tm = fmaxf(tm, __shfl_xor(tm, 8));
      float mn = fmaxf(m[j], tm);
      float al = expf(m[j] - mn);
      m[j] = mn;
      float ps = 0.f;
#pragma unroll
      for (int ni = 0; ni < 4; ++ni) {
        float pv = expf(s[ni][j] - mn);
        s[ni][j] = pv;
        ps += pv;
      }
      ps += __shfl_xor(ps, 1);
      ps += __shfl_xor(ps, 2);
      ps += __shfl_xor(ps, 4);
      ps += __shfl_xor(ps, 8);
      l[j] = l[j] * al + ps;
#pragma unroll
      for (int ni = 0; ni < 4; ++ni) o[ni][j] *= al;
    }

    // P -> LDS (bf16), wave-private (same-wave in-order LDS)
#pragma unroll
    for (int ni = 0; ni < 4; ++ni)
#pragma unroll
      for (int j = 0; j < 4; ++j)
        Ps[w][(lane >> 4) * 4 + j][ni * 16 + fr] = f2bf(s[ni][j]);
    asm volatile("s_waitcnt lgkmcnt(0)" ::: "memory");

    // PV
    bf16x8 pf0 = *(const bf16x8*)&Ps[w][fr][fk];
    bf16x8 pf1 = *(const bf16x8*)&Ps[w][fr][fk + 32];
    __builtin_amdgcn_s_setprio(1);
#pragma unroll
    for (int ni = 0; ni < 4; ++ni) {
      bf16x8 vf0 = *(const bf16x8*)&Vt[ni * 16 + fr][fk];
      bf16x8 vf1 = *(const bf16x8*)&Vt[ni * 16 + fr][fk + 32];
      o[ni] = __builtin_amdgcn_mfma_f32_16x16x32_bf16(pf0, vf0, o[ni], 0, 0, 0);
      o[ni] = __builtin_amdgcn_mfma_f32_16x16x32_bf16(pf1, vf1, o[ni], 0, 0, 0);
    }
    __builtin_amdgcn_s_setprio(0);
  }

#pragma unroll
  for (int j = 0; j < 4; ++j) {
    float inv = 1.0f / l[j];
    int q = qminw + (lane >> 4) * 4 + j;
    u16* op = out + ((size_t)(b * TSEQ) + q) * DMODEL + h * HDIM + fr;
#pragma unroll
    for (int ni = 0; ni < 4; ++ni)
      op[ni * 16] = f2bf(o[ni][j] * inv);
  }
}

// ------------------------------ launcher ----------------------------------
extern "C" void kernel_launch(void* const* d_in, const int* in_sizes, int n_in,
                              void* d_out, int out_size, void* d_ws, size_t ws_size,
                              hipStream_t stream) {
  const int*   ids    = (const int*)d_in[0];
  const float* emb    = (const float*)d_in[1];
  const float* pos    = (const float*)d_in[2];
  const float* ln1_g  = (const float*)d_in[3];
  const float* ln1_b  = (const float*)d_in[4];
  const float* ln2_g  = (const float*)d_in[5];
  const float* ln2_b  = (const float*)d_in[6];
  const float* qkv_w  = (const float*)d_in[7];
  const float* out_w  = (const float*)d_in[8];
  const float* mlp_w1 = (const float*)d_in[9];
  const float* mlp_b1 = (const float*)d_in[10];
  const float* mlp_w2 = (const float*)d_in[11];
  const float* mlp_b2 = (const float*)d_in[12];
  const float* lnf_g  = (const float*)d_in[13];
  const float* lnf_b  = (const float*)d_in[14];
  float* outp = (float*)d_out;

  const int M = BATCH * TSEQ;                         // 4096
  char* p = (char*)d_ws;
  float* x    = (float*)p;  p += (size_t)M * DMODEL * 4;       // 16.78 MB
  u16*   yb   = (u16*)p;    p += (size_t)M * DMODEL * 2;       //  8.39 MB
  u16*   qkvb = (u16*)p;    p += (size_t)M * 3 * DMODEL * 2;   // 25.17 MB
  u16*   mid  = (u16*)p;    p += (size_t)M * DFFN * 2;         // 33.55 MB
  u16*   wq   = (u16*)p;    p += (size_t)3 * DMODEL * DMODEL * 2;
  u16*   wo   = (u16*)p;    p += (size_t)DMODEL * DMODEL * 2;
  u16*   w1   = (u16*)p;    p += (size_t)DFFN * DMODEL * 2;
  u16*   w2   = (u16*)p;    p += (size_t)DMODEL * DFFN * 2;    // ~109 MB total
  u16*   embb = qkvb;  // final stage: reuse qkvb+mid+wq (all dead), 65.5 MB

  embed_kernel<<<M, 256, 0, stream>>>(ids, emb, pos, x);

  for (int l = 0; l < NLAYER; ++l) {
    cvt_bf16_kernel<<<1536, 256, 0, stream>>>(qkv_w  + (size_t)l * 3 * DMODEL * DMODEL, wq);
    cvt_bf16_kernel<<< 512, 256, 0, stream>>>(out_w  + (size_t)l * DMODEL * DMODEL,     wo);
    cvt_bf16_kernel<<<2048, 256, 0, stream>>>(mlp_w1 + (size_t)l * DFFN * DMODEL,       w1);
    cvt_bf16_kernel<<<2048, 256, 0, stream>>>(mlp_w2 + (size_t)l * DMODEL * DFFN,       w2);

    ln_kernel<<<M, 256, 0, stream>>>(x, ln1_g + l * DMODEL, ln1_b + l * DMODEL, yb);
    gemm_mfma<0, false, false, true><<<dim3(3 * DMODEL / 128, M / 128), 256, 0, stream>>>(
        (const bf16_t*)yb, (const bf16_t*)wq, nullptr, nullptr, qkvb, M, 3 * DMODEL, DMODEL);
    attn_mfma_kernel<<<dim3(TSEQ / 64, BATCH * NHEAD), 256, 0, stream>>>(qkvb, yb);
    gemm_mfma<0, false, true, false><<<dim3(DMODEL / 128, M / 128), 256, 0, stream>>>(
        (const bf16_t*)yb, (const bf16_t*)wo, nullptr, x, x, M, DMODEL, DMODEL);
    ln_kernel<<<M, 256, 0, stream>>>(x, ln2_g + l * DMODEL, ln2_b + l * DMODEL, yb);
    gemm_mfma<1, true, false, true><<<dim3(DFFN / 128, M / 128), 256, 0, stream>>>(
        (const bf16_t*)yb, (const bf16_t*)w1, mlp_b1 + (size_t)l * DFFN, nullptr, mid,
        M, DFFN, DMODEL);
    gemm_mfma<0, true, true, false><<<dim3(DMODEL / 128, M / 128), 256, 0, stream>>>(
        (const bf16_t*)mid, (const bf16_t*)w2, mlp_b2 + (size_t)l * DMODEL, x, x,
        M, DMODEL, DFFN);
  }

  ln_kernel<<<M, 256, 0, stream>>>(x, lnf_g, lnf_b, yb);
  cvt_bf16_kernel<<<16000, 256, 0, stream>>>(emb, embb);
  gemm_mfma<0, false, false, false><<<dim3(NVOCAB / 128, M / 128), 256, 0, stream>>>(
      (const bf16_t*)yb, (const bf16_t*)embb, nullptr, nullptr, outp, M, NVOCAB, DMODEL);
}

// Round 5
// 2570.700 us; speedup vs baseline: 11.0008x; 1.0997x over previous
//
#include <hip/hip_runtime.h>
#include <math.h>

#define TSEQ   2048
#define BATCH  2
#define DMODEL 1024
#define NLAYER 6
#define NHEAD  16
#define HDIM   64
#define DFFN   4096
#define NVOCAB 32000
#define LNEPS  1e-5f

typedef __bf16 bf16_t;
typedef bf16_t bf16x8 __attribute__((ext_vector_type(8)));
typedef float  f32x4  __attribute__((ext_vector_type(4)));
typedef unsigned short u16;
typedef u16 u16x4 __attribute__((ext_vector_type(4)));
typedef u16 u16x8 __attribute__((ext_vector_type(8)));

#define GBAR()   __builtin_amdgcn_s_barrier()
#define WLGKM0() asm volatile("s_waitcnt lgkmcnt(0)" ::: "memory")
#define WVM4()   asm volatile("s_waitcnt vmcnt(4)" ::: "memory")
#define WVM0()   asm volatile("s_waitcnt vmcnt(0)" ::: "memory")

__device__ __forceinline__ u16 f2bf(float f) {   // RNE fp32 -> bf16 bits
  unsigned u = __float_as_uint(f);
  return (u16)((u + 0x7fffu + ((u >> 16) & 1u)) >> 16);
}

__device__ __forceinline__ void gload16(const void* g, void* l) {
  __builtin_amdgcn_global_load_lds(
      (const __attribute__((address_space(1))) unsigned int*)g,
      (__attribute__((address_space(3))) unsigned int*)l, 16, 0, 0);
}

// ----------------------------- embedding ---------------------------------
__global__ __launch_bounds__(256) void embed_kernel(
    const int* __restrict__ ids, const float* __restrict__ emb,
    const float* __restrict__ pos, float* __restrict__ x) {
  int bt  = blockIdx.x;
  int t   = bt & (TSEQ - 1);
  int id  = ids[bt];
  int tid = threadIdx.x;
  float4 e = ((const float4*)(emb + (size_t)id * DMODEL))[tid];
  float4 p = ((const float4*)(pos + (size_t)t  * DMODEL))[tid];
  float4 r;
  r.x = e.x + p.x; r.y = e.y + p.y; r.z = e.z + p.z; r.w = e.w + p.w;
  ((float4*)(x + (size_t)bt * DMODEL))[tid] = r;
}

// ------------------------- fp32 -> bf16 convert ---------------------------
__global__ __launch_bounds__(256) void cvt_bf16_kernel(
    const float* __restrict__ in, u16* __restrict__ out) {
  size_t i = ((size_t)blockIdx.x * 256 + threadIdx.x) * 8;
  float4 a = *(const float4*)(in + i);
  float4 b = *(const float4*)(in + i + 4);
  u16x8 r;
  r[0] = f2bf(a.x); r[1] = f2bf(a.y); r[2] = f2bf(a.z); r[3] = f2bf(a.w);
  r[4] = f2bf(b.x); r[5] = f2bf(b.y); r[6] = f2bf(b.z); r[7] = f2bf(b.w);
  *(u16x8*)(out + i) = r;
}

// ------------------------- layernorm (bf16 out) ---------------------------
__global__ __launch_bounds__(256) void ln_kernel(
    const float* __restrict__ x, const float* __restrict__ g,
    const float* __restrict__ b, u16* __restrict__ y) {
  int row = blockIdx.x, tid = threadIdx.x;
  int lane = tid & 63, w = tid >> 6;
  float4 v = ((const float4*)(x + (size_t)row * DMODEL))[tid];
  float s = v.x + v.y + v.z + v.w;
#pragma unroll
  for (int o = 32; o >= 1; o >>= 1) s += __shfl_xor(s, o);
  __shared__ float red[8];
  if (lane == 0) red[w] = s;
  __syncthreads();
  float mu = (red[0] + red[1] + red[2] + red[3]) * (1.0f / DMODEL);
  float d0 = v.x - mu, d1 = v.y - mu, d2 = v.z - mu, d3 = v.w - mu;
  float s2 = d0*d0 + d1*d1 + d2*d2 + d3*d3;
#pragma unroll
  for (int o = 32; o >= 1; o >>= 1) s2 += __shfl_xor(s2, o);
  if (lane == 0) red[4 + w] = s2;
  __syncthreads();
  float var = (red[4] + red[5] + red[6] + red[7]) * (1.0f / DMODEL);
  float rs = rsqrtf(var + LNEPS);
  float4 gv = ((const float4*)g)[tid];
  float4 bv = ((const float4*)b)[tid];
  u16x4 r;
  r[0] = f2bf(d0 * rs * gv.x + bv.x);
  r[1] = f2bf(d1 * rs * gv.y + bv.y);
  r[2] = f2bf(d2 * rs * gv.z + bv.z);
  r[3] = f2bf(d3 * rs * gv.w + bv.w);
  ((u16x4*)(y + (size_t)row * DMODEL))[tid] = r;
}

__device__ __forceinline__ float gelu_f(float v) {
  return 0.5f * v * (1.0f + erff(v * 0.70710678118654752f));
}

// ------------------- 128x128 MFMA GEMM (small-N cases) ---------------------
template<int ACT, bool BIAS, bool RES, bool OUTBF>
__global__ __launch_bounds__(256) void gemm_mfma(
    const bf16_t* __restrict__ A, const bf16_t* __restrict__ W,
    const float* __restrict__ bias, const float* __restrict__ res,
    void* __restrict__ Cout, int M, int N, int K) {
  __shared__ bf16_t As[128 * 32];
  __shared__ bf16_t Ws[128 * 32];
  const int tid  = threadIdx.x;
  const int lane = tid & 63, w = tid >> 6;
  const int wr = w >> 1, wc = w & 1;

  const int gx  = gridDim.x;
  const int bid = blockIdx.y * gx + blockIdx.x;
  const int cpx = (gx * 32) >> 3;                 // nwg/8 (nwg%8==0)
  const int swz = (bid & 7) * cpx + (bid >> 3);
  const int m0 = (swz & 31) * 128;
  const int n0 = (swz >> 5) * 128;

  const size_t stride = (size_t)K * 2;
  const int srow = lane >> 2;
  const int scol = (lane & 3) * 16;

  const char* gA0 = (const char*)A + ((size_t)(m0 + w * 32 + srow)) * stride + scol;
  const char* gA1 = gA0 + 16 * stride;
  const char* gW0 = (const char*)W + ((size_t)(n0 + w * 32 + srow)) * stride + scol;
  const char* gW1 = gW0 + 16 * stride;
  char* lA0 = (char*)As + (w * 32) * 64;
  char* lA1 = lA0 + 16 * 64;
  char* lW0 = (char*)Ws + (w * 32) * 64;
  char* lW1 = lW0 + 16 * 64;

  f32x4 acc[4][4] = {};

  for (int k0 = 0; k0 < K; k0 += 32) {
    gload16(gA0, lA0); gload16(gA1, lA1);
    gload16(gW0, lW0); gload16(gW1, lW1);
    gA0 += 64; gA1 += 64; gW0 += 64; gW1 += 64;
    __syncthreads();
    bf16x8 afr[4], bfr[4];
    const int kb = (lane >> 4) * 16;
    const int rr = lane & 15;
#pragma unroll
    for (int t = 0; t < 4; ++t) {
      afr[t] = *(const bf16x8*)((const char*)As + (wr * 64 + t * 16 + rr) * 64 + kb);
      bfr[t] = *(const bf16x8*)((const char*)Ws + (wc * 64 + t * 16 + rr) * 64 + kb);
    }
#pragma unroll
    for (int mi = 0; mi < 4; ++mi)
#pragma unroll
      for (int ni = 0; ni < 4; ++ni)
        acc[mi][ni] = __builtin_amdgcn_mfma_f32_16x16x32_bf16(
            afr[mi], bfr[ni], acc[mi][ni], 0, 0, 0);
    __syncthreads();
  }

  const int r4 = (lane >> 4) * 4;
  const int cc = lane & 15;
#pragma unroll
  for (int mi = 0; mi < 4; ++mi) {
#pragma unroll
    for (int ni = 0; ni < 4; ++ni) {
      const int col = n0 + wc * 64 + ni * 16 + cc;
      float bv = 0.f;
      if (BIAS) bv = bias[col];
#pragma unroll
      for (int j = 0; j < 4; ++j) {
        const int row = m0 + wr * 64 + mi * 16 + r4 + j;
        float u = acc[mi][ni][j] + bv;
        if (ACT == 1) u = gelu_f(u);
        if (RES) u += res[(size_t)row * N + col];
        if (OUTBF) ((u16*)Cout)[(size_t)row * N + col] = f2bf(u);
        else       ((float*)Cout)[(size_t)row * N + col] = u;
      }
    }
  }
}

// --------------- 256x256 8-phase MFMA GEMM (big-N cases) -------------------
// C[M,N] = A[M,K]*W[N,K]^T (+bias)(+gelu). M==4096, N%256==0, K%128==0.
// 8 waves (2M x 4N), BK=64, LDS 128 KiB double-buffered, quarter-XOR swizzle
// (q ^= row&7, pre-swizzled global src + swizzled ds_read). Counted vmcnt(4)
// at phases 4/8 only; stage slots hazard-scheduled (B after ph1/5, A after
// ph4/8, one barrier+lgkmcnt between last read and re-stage of a region).
__device__ __forceinline__ bf16x8 ldsrd(const char* p) {
  return *(const bf16x8*)p;
}

template<int QD>
__device__ __forceinline__ void rd_a(bf16x8 (&afr)[2][2], const char* base,
                                     int aB0, int aB1) {
  afr[0][0] = ldsrd(base + aB0 + QD * 4096);
  afr[0][1] = ldsrd(base + aB1 + QD * 4096);
  afr[1][0] = ldsrd(base + aB0 + QD * 4096 + 2048);
  afr[1][1] = ldsrd(base + aB1 + QD * 4096 + 2048);
}

__device__ __forceinline__ void rd_b(bf16x8 (&bfr)[4][2], const char* base,
                                     int bB0, int bB1) {
#pragma unroll
  for (int ni = 0; ni < 4; ++ni) {
    bfr[ni][0] = ldsrd(base + bB0 + ni * 2048);
    bfr[ni][1] = ldsrd(base + bB1 + ni * 2048);
  }
}

template<int QD>
__device__ __forceinline__ void mm16(f32x4 (&acc)[8][4], bf16x8 (&afr)[2][2],
                                     bf16x8 (&bfr)[4][2]) {
#pragma unroll
  for (int ni = 0; ni < 4; ++ni) {
    acc[QD*2+0][ni] = __builtin_amdgcn_mfma_f32_16x16x32_bf16(afr[0][0], bfr[ni][0], acc[QD*2+0][ni], 0, 0, 0);
    acc[QD*2+0][ni] = __builtin_amdgcn_mfma_f32_16x16x32_bf16(afr[0][1], bfr[ni][1], acc[QD*2+0][ni], 0, 0, 0);
    acc[QD*2+1][ni] = __builtin_amdgcn_mfma_f32_16x16x32_bf16(afr[1][0], bfr[ni][0], acc[QD*2+1][ni], 0, 0, 0);
    acc[QD*2+1][ni] = __builtin_amdgcn_mfma_f32_16x16x32_bf16(afr[1][1], bfr[ni][1], acc[QD*2+1][ni], 0, 0, 0);
  }
}

template<int ACT, bool BIAS, bool OUTBF>
__global__ __launch_bounds__(512, 2) void gemm_mfma256(
    const bf16_t* __restrict__ A, const bf16_t* __restrict__ W,
    const float* __restrict__ bias, void* __restrict__ Cout,
    int M, int N, int K) {
  __shared__ char lds[131072];
  char* Asc = lds;                 // 2 bufs x 32768 (256 rows x 128 B)
  char* Bsc = lds + 65536;

  const int tid  = threadIdx.x;
  const int lane = tid & 63;
  const int w    = tid >> 6;
  const int wr   = w >> 2, wc = w & 3;

  // XCD swizzle, m-fast within chunk (M/256 == 16 tiles, nwg % 8 == 0)
  const int nwg = gridDim.x * gridDim.y;
  const int bid = blockIdx.y * gridDim.x + blockIdx.x;
  const int swz = (bid & 7) * (nwg >> 3) + (bid >> 3);
  const int m0 = (swz & 15) << 8;
  const int n0 = (swz >> 4) << 8;

  const size_t K2 = (size_t)K * 2;
  const int KT = K >> 6;                       // 64-element k-tiles

  // staging: thread covers row (tid>>3), physical quarter tid&7;
  // source fetches logical quarter (tid&7) ^ ((tid>>3)&7)  [pre-swizzle]
  const int qsrc = (((tid & 7) ^ ((tid >> 3) & 7)) << 4);
  const char* srcA = (const char*)A + (size_t)(m0 + (tid >> 3)) * K2 + qsrc;
  const char* srcB = (const char*)W + (size_t)(n0 + (tid >> 3)) * K2 + qsrc;
  char* dstA = Asc + (tid & 448) * 16;         // wave-uniform base (w*1024)
  char* dstB = Bsc + (tid & 448) * 16;

  // parts: 0=B half0, 1=B half1, 2=A half0, 3=A half1
  auto STG = [&](int kt, int part) {
    if (kt >= KT) return;
    const int h = part & 1;
    const size_t so = (size_t)(h * 128) * K2 + (size_t)kt * 128;
    const int dofs = ((kt & 1) << 15) + (h << 14);
    if (part >= 2) {
      gload16(srcA + so, dstA + dofs);
      gload16(srcA + so + 64 * K2, dstA + dofs + 8192);
    } else {
      gload16(srcB + so, dstB + dofs);
      gload16(srcB + so + 64 * K2, dstB + dofs + 8192);
    }
  };

  // ds_read fragment offsets: row = (wr*128|wc*64) + idx*16 + rr;
  // byte = row*128 + ((q_log ^ (row&7))*16); row&7 == lane&7 here.
  const int rr = lane & 15;
  const int q0 = (((lane >> 4) ^ (lane & 7)) << 4);
  const int aB0 = ((wr << 7) + rr) * 128 + q0;
  const int aB1 = ((wr << 7) + rr) * 128 + (q0 ^ 64);
  const int bB0 = ((wc << 6) + rr) * 128 + q0;
  const int bB1 = ((wc << 6) + rr) * 128 + (q0 ^ 64);

  bf16x8 bfr[4][2];
  bf16x8 afr[2][2];
  f32x4 acc[8][4] = {};

  // prologue: k0 fully + k1's B halves; k0 landed (<=2 halves in flight)
  STG(0, 0); STG(0, 1); STG(0, 2); STG(0, 3);
  STG(1, 0); STG(1, 1);
  WVM4();
  GBAR();

  const int iters = KT >> 1;
  for (int t = 0; t < iters; ++t) {
    const int d = t << 1;
    // ---- phase 1: k-tile d (buf0), quadrant 0 ----
    rd_b(bfr, Bsc, bB0, bB1);
    rd_a<0>(afr, Asc, aB0, aB1);
    STG(d + 1, 2); STG(d + 1, 3);
    GBAR(); WLGKM0();
    __builtin_amdgcn_s_setprio(1); mm16<0>(acc, afr, bfr); __builtin_amdgcn_s_setprio(0);
    GBAR();
    // ---- phase 2 ----
    rd_a<1>(afr, Asc, aB0, aB1);
    STG(d + 2, 0);
    GBAR(); WLGKM0();
    __builtin_amdgcn_s_setprio(1); mm16<1>(acc, afr, bfr); __builtin_amdgcn_s_setprio(0);
    GBAR();
    // ---- phase 3 ----
    rd_a<2>(afr, Asc, aB0, aB1);
    STG(d + 2, 1);
    GBAR(); WLGKM0();
    __builtin_amdgcn_s_setprio(1); mm16<2>(acc, afr, bfr); __builtin_amdgcn_s_setprio(0);
    GBAR();
    // ---- phase 4 ----
    rd_a<3>(afr, Asc, aB0, aB1);
    GBAR(); WLGKM0();
    __builtin_amdgcn_s_setprio(1); mm16<3>(acc, afr, bfr); __builtin_amdgcn_s_setprio(0);
    if (t == iters - 1) { WVM0(); } else { WVM4(); }   // k-tile d+1 landed
    GBAR();
    // ---- phase 5: k-tile d+1 (buf1), quadrant 0 ----
    rd_b(bfr, Bsc + 32768, bB0, bB1);
    rd_a<0>(afr, Asc + 32768, aB0, aB1);
    STG(d + 2, 2);
    GBAR(); WLGKM0();
    __builtin_amdgcn_s_setprio(1); mm16<0>(acc, afr, bfr); __builtin_amdgcn_s_setprio(0);
    GBAR();
    // ---- phase 6 ----
    rd_a<1>(afr, Asc + 32768, aB0, aB1);
    STG(d + 2, 3);
    GBAR(); WLGKM0();
    __builtin_amdgcn_s_setprio(1); mm16<1>(acc, afr, bfr); __builtin_amdgcn_s_setprio(0);
    GBAR();
    // ---- phase 7 ----
    rd_a<2>(afr, Asc + 32768, aB0, aB1);
    STG(d + 3, 0);
    GBAR(); WLGKM0();
    __builtin_amdgcn_s_setprio(1); mm16<2>(acc, afr, bfr); __builtin_amdgcn_s_setprio(0);
    GBAR();
    // ---- phase 8 ----
    rd_a<3>(afr, Asc + 32768, aB0, aB1);
    STG(d + 3, 1);
    GBAR(); WLGKM0();
    __builtin_amdgcn_s_setprio(1); mm16<3>(acc, afr, bfr); __builtin_amdgcn_s_setprio(0);
    WVM4();                                            // k-tile d+2 landed
    GBAR();
  }

  // ---- epilogue ----
  const int r4 = (lane >> 4) << 2;
  const int cc = lane & 15;
  const int orow0 = m0 + wr * 128;
  const int ocol0 = n0 + wc * 64;
#pragma unroll
  for (int mi = 0; mi < 8; ++mi) {
#pragma unroll
    for (int ni = 0; ni < 4; ++ni) {
      const int col = ocol0 + ni * 16 + cc;
      float bv = 0.f;
      if (BIAS) bv = bias[col];
#pragma unroll
      for (int j = 0; j < 4; ++j) {
        const int row = orow0 + mi * 16 + r4 + j;
        float u = acc[mi][ni][j] + bv;
        if (ACT == 1) u = gelu_f(u);
        if (OUTBF) ((u16*)Cout)[(size_t)row * N + col] = f2bf(u);
        else       ((float*)Cout)[(size_t)row * N + col] = u;
      }
    }
  }
}

// ----------------------- MFMA flash attention -----------------------------
__global__ __launch_bounds__(256) void attn_mfma_kernel(
    const u16* __restrict__ qkv, u16* __restrict__ out) {
  const int qb0 = blockIdx.x * 64;
  const int bh  = blockIdx.y;
  const int b = bh >> 4, h = bh & 15;
  const int tid = threadIdx.x;
  const int lane = tid & 63, w = tid >> 6;

  __shared__ u16 Ks[64][72];
  __shared__ u16 Vt[64][72];
  __shared__ u16 Ps[4][16][72];

  const size_t rowstr = 3 * DMODEL;
  const u16* base = qkv + (size_t)b * TSEQ * rowstr;

  const int fr = lane & 15;
  const int fk = (lane >> 4) * 8;
  const int qminw = qb0 + w * 16;
  const int qrow = qminw + fr;

  u16x8 q0r = *(const u16x8*)(base + (size_t)qrow * rowstr + h * HDIM + fk);
  u16x8 q1r = *(const u16x8*)(base + (size_t)qrow * rowstr + h * HDIM + fk + 32);
  bf16x8 qf0, qf1;
#pragma unroll
  for (int i = 0; i < 8; ++i) {
    ((u16*)&qf0)[i] = f2bf(__uint_as_float((unsigned)q0r[i] << 16) * 0.125f);
    ((u16*)&qf1)[i] = f2bf(__uint_as_float((unsigned)q1r[i] << 16) * 0.125f);
  }

  f32x4 o[4] = {};
  float m[4] = {-1e30f, -1e30f, -1e30f, -1e30f};
  float l[4] = {0.f, 0.f, 0.f, 0.f};

  const int skr = tid >> 2;
  const int skc = (tid & 3) * 16;
  const int vk0 = (tid & 31) * 2;
  const int vd0 = (tid >> 5) * 8;

  u16x8 kA, kB, vA, vB;
  {
    const u16* kr = base + (size_t)skr * rowstr + DMODEL + h * HDIM + skc;
    kA = *(const u16x8*)kr; kB = *(const u16x8*)(kr + 8);
    const u16* vr = base + (size_t)vk0 * rowstr + 2 * DMODEL + h * HDIM + vd0;
    vA = *(const u16x8*)vr; vB = *(const u16x8*)(vr + rowstr);
  }

  for (int s0 = 0; s0 <= qb0; s0 += 64) {
    __syncthreads();
    *(u16x8*)&Ks[skr][skc]     = kA;
    *(u16x8*)&Ks[skr][skc + 8] = kB;
#pragma unroll
    for (int i = 0; i < 8; ++i) {
      unsigned pk = (unsigned)vA[i] | ((unsigned)vB[i] << 16);
      *(unsigned*)&Vt[vd0 + i][vk0] = pk;
    }
    __syncthreads();

    if (s0 + 64 <= qb0) {
      const u16* kr = base + (size_t)(s0 + 64 + skr) * rowstr + DMODEL + h * HDIM + skc;
      kA = *(const u16x8*)kr; kB = *(const u16x8*)(kr + 8);
      const u16* vr = base + (size_t)(s0 + 64 + vk0) * rowstr + 2 * DMODEL + h * HDIM + vd0;
      vA = *(const u16x8*)vr; vB = *(const u16x8*)(vr + rowstr);
    }

    f32x4 s[4] = {};
    __builtin_amdgcn_s_setprio(1);
#pragma unroll
    for (int ni = 0; ni < 4; ++ni) {
      bf16x8 kf0 = *(const bf16x8*)&Ks[ni * 16 + fr][fk];
      bf16x8 kf1 = *(const bf16x8*)&Ks[ni * 16 + fr][fk + 32];
      s[ni] = __builtin_amdgcn_mfma_f32_16x16x32_bf16(qf0, kf0, s[ni], 0, 0, 0);
      s[ni] = __builtin_amdgcn_mfma_f32_16x16x32_bf16(qf1, kf1, s[ni], 0, 0, 0);
    }
    __builtin_amdgcn_s_setprio(0);

    if (s0 + 63 > qminw) {
      const int key0 = s0 + fr;
      const int q0_  = qminw + (lane >> 4) * 4;
#pragma unroll
      for (int ni = 0; ni < 4; ++ni)
#pragma unroll
        for (int j = 0; j < 4; ++j)
          if (key0 + ni * 16 > q0_ + j) s[ni][j] = -3e38f;
    }

    float p_[4];
#pragma unroll
    for (int j = 0; j < 4; ++j) {
      float tm = fmaxf(fmaxf(s[0][j], s[1][j]), fmaxf(s[2][j], s[3][j]));
      tm = fmaxf(tm, __shfl_xor(tm, 1));
      tm = fmaxf(tm, __shfl_xor(tm, 2));
      tm = fmaxf(tm, __shfl_xor(tm, 4));
      tm = fmaxf(tm, __shfl_xor(tm, 8));
      float mn = fmaxf(m[j], tm);
      float al = expf(m[j] - mn);
      m[j] = mn;
      float ps = 0.f;
#pragma unroll
      for (int ni = 0; ni < 4; ++ni) {
        float pv = expf(s[ni][j] - mn);
        s[ni][j] = pv;
        ps += pv;
      }
      ps += __shfl_xor(ps, 1);
      ps += __shfl_xor(ps, 2);
      ps += __shfl_xor(ps, 4);
      ps += __shfl_xor(ps, 8);
      l[j] = l[j] * al + ps;
#pragma unroll
      for (int ni = 0; ni < 4; ++ni) o[ni][j] *= al;
      p_[j] = ps;  (void)p_[j];
    }

#pragma unroll
    for (int ni = 0; ni < 4; ++ni)
#pragma unroll
      for (int j = 0; j < 4; ++j)
        Ps[w][(lane >> 4) * 4 + j][ni * 16 + fr] = f2bf(s[ni][j]);
    asm volatile("s_waitcnt lgkmcnt(0)" ::: "memory");

    bf16x8 pf0 = *(const bf16x8*)&Ps[w][fr][fk];
    bf16x8 pf1 = *(const bf16x8*)&Ps[w][fr][fk + 32];
    __builtin_amdgcn_s_setprio(1);
#pragma unroll
    for (int ni = 0; ni < 4; ++ni) {
      bf16x8 vf0 = *(const bf16x8*)&Vt[ni * 16 + fr][fk];
      bf16x8 vf1 = *(const bf16x8*)&Vt[ni * 16 + fr][fk + 32];
      o[ni] = __builtin_amdgcn_mfma_f32_16x16x32_bf16(pf0, vf0, o[ni], 0, 0, 0);
      o[ni] = __builtin_amdgcn_mfma_f32_16x16x32_bf16(pf1, vf1, o[ni], 0, 0, 0);
    }
    __builtin_amdgcn_s_setprio(0);
  }

#pragma unroll
  for (int j = 0; j < 4; ++j) {
    float inv = 1.0f / l[j];
    int q = qminw + (lane >> 4) * 4 + j;
    u16* op = out + ((size_t)(b * TSEQ) + q) * DMODEL + h * HDIM + fr;
#pragma unroll
    for (int ni = 0; ni < 4; ++ni)
      op[ni * 16] = f2bf(o[ni][j] * inv);
  }
}

// ------------------------------ launcher ----------------------------------
extern "C" void kernel_launch(void* const* d_in, const int* in_sizes, int n_in,
                              void* d_out, int out_size, void* d_ws, size_t ws_size,
                              hipStream_t stream) {
  const int*   ids    = (const int*)d_in[0];
  const float* emb    = (const float*)d_in[1];
  const float* pos    = (const float*)d_in[2];
  const float* ln1_g  = (const float*)d_in[3];
  const float* ln1_b  = (const float*)d_in[4];
  const float* ln2_g  = (const float*)d_in[5];
  const float* ln2_b  = (const float*)d_in[6];
  const float* qkv_w  = (const float*)d_in[7];
  const float* out_w  = (const float*)d_in[8];
  const float* mlp_w1 = (const float*)d_in[9];
  const float* mlp_b1 = (const float*)d_in[10];
  const float* mlp_w2 = (const float*)d_in[11];
  const float* mlp_b2 = (const float*)d_in[12];
  const float* lnf_g  = (const float*)d_in[13];
  const float* lnf_b  = (const float*)d_in[14];
  float* outp = (float*)d_out;

  const int M = BATCH * TSEQ;                         // 4096
  char* p = (char*)d_ws;
  float* x    = (float*)p;  p += (size_t)M * DMODEL * 4;
  u16*   yb   = (u16*)p;    p += (size_t)M * DMODEL * 2;
  u16*   qkvb = (u16*)p;    p += (size_t)M * 3 * DMODEL * 2;
  u16*   mid  = (u16*)p;    p += (size_t)M * DFFN * 2;
  u16*   wq   = (u16*)p;    p += (size_t)3 * DMODEL * DMODEL * 2;
  u16*   wo   = (u16*)p;    p += (size_t)DMODEL * DMODEL * 2;
  u16*   w1   = (u16*)p;    p += (size_t)DFFN * DMODEL * 2;
  u16*   w2   = (u16*)p;    p += (size_t)DMODEL * DFFN * 2;
  u16*   embb = qkvb;  // final stage: reuse qkvb+mid+wq/wo (all dead)

  embed_kernel<<<M, 256, 0, stream>>>(ids, emb, pos, x);

  for (int l = 0; l < NLAYER; ++l) {
    cvt_bf16_kernel<<<1536, 256, 0, stream>>>(qkv_w  + (size_t)l * 3 * DMODEL * DMODEL, wq);
    cvt_bf16_kernel<<< 512, 256, 0, stream>>>(out_w  + (size_t)l * DMODEL * DMODEL,     wo);
    cvt_bf16_kernel<<<2048, 256, 0, stream>>>(mlp_w1 + (size_t)l * DFFN * DMODEL,       w1);
    cvt_bf16_kernel<<<2048, 256, 0, stream>>>(mlp_w2 + (size_t)l * DMODEL * DFFN,       w2);

    ln_kernel<<<M, 256, 0, stream>>>(x, ln1_g + l * DMODEL, ln1_b + l * DMODEL, yb);
    gemm_mfma256<0, false, true><<<dim3(3 * DMODEL / 256, M / 256), 512, 0, stream>>>(
        (const bf16_t*)yb, (const bf16_t*)wq, nullptr, qkvb, M, 3 * DMODEL, DMODEL);
    attn_mfma_kernel<<<dim3(TSEQ / 64, BATCH * NHEAD), 256, 0, stream>>>(qkvb, yb);
    gemm_mfma<0, false, true, false><<<dim3(DMODEL / 128, M / 128), 256, 0, stream>>>(
        (const bf16_t*)yb, (const bf16_t*)wo, nullptr, x, x, M, DMODEL, DMODEL);
    ln_kernel<<<M, 256, 0, stream>>>(x, ln2_g + l * DMODEL, ln2_b + l * DMODEL, yb);
    gemm_mfma256<1, true, true><<<dim3(DFFN / 256, M / 256), 512, 0, stream>>>(
        (const bf16_t*)yb, (const bf16_t*)w1, mlp_b1 + (size_t)l * DFFN, mid,
        M, DFFN, DMODEL);
    gemm_mfma<0, true, true, false><<<dim3(DMODEL / 128, M / 128), 256, 0, stream>>>(
        (const bf16_t*)mid, (const bf16_t*)w2, mlp_b2 + (size_t)l * DMODEL, x, x,
        M, DMODEL, DFFN);
  }

  ln_kernel<<<M, 256, 0, stream>>>(x, lnf_g, lnf_b, yb);
  cvt_bf16_kernel<<<16000, 256, 0, stream>>>(emb, embb);
  gemm_mfma256<0, false, false><<<dim3(NVOCAB / 256, M / 256), 512, 0, stream>>>(
      (const bf16_t*)yb, (const bf16_t*)embb, nullptr, outp, M, NVOCAB, DMODEL);
}

// Round 6
// 2499.952 us; speedup vs baseline: 11.3121x; 1.0283x over previous
//
#include <hip/hip_runtime.h>
#include <math.h>

#define TSEQ   2048
#define BATCH  2
#define DMODEL 1024
#define NLAYER 6
#define NHEAD  16
#define HDIM   64
#define DFFN   4096
#define NVOCAB 32000
#define LNEPS  1e-5f

typedef __bf16 bf16_t;
typedef bf16_t bf16x8 __attribute__((ext_vector_type(8)));
typedef float  f32x4  __attribute__((ext_vector_type(4)));
typedef unsigned short u16;
typedef u16 u16x4 __attribute__((ext_vector_type(4)));
typedef u16 u16x8 __attribute__((ext_vector_type(8)));

#define GBAR()   __builtin_amdgcn_s_barrier()
#define WLGKM0() asm volatile("s_waitcnt lgkmcnt(0)" ::: "memory")
#define WVM4()   asm volatile("s_waitcnt vmcnt(4)" ::: "memory")
#define WVM0()   asm volatile("s_waitcnt vmcnt(0)" ::: "memory")

__device__ __forceinline__ u16 f2bf(float f) {   // RNE fp32 -> bf16 bits
  unsigned u = __float_as_uint(f);
  return (u16)((u + 0x7fffu + ((u >> 16) & 1u)) >> 16);
}

__device__ __forceinline__ void gload16(const void* g, void* l) {
  __builtin_amdgcn_global_load_lds(
      (const __attribute__((address_space(1))) unsigned int*)g,
      (__attribute__((address_space(3))) unsigned int*)l, 16, 0, 0);
}

// ----------------------------- embedding ---------------------------------
__global__ __launch_bounds__(256) void embed_kernel(
    const int* __restrict__ ids, const float* __restrict__ emb,
    const float* __restrict__ pos, float* __restrict__ x) {
  int bt  = blockIdx.x;
  int t   = bt & (TSEQ - 1);
  int id  = ids[bt];
  int tid = threadIdx.x;
  float4 e = ((const float4*)(emb + (size_t)id * DMODEL))[tid];
  float4 p = ((const float4*)(pos + (size_t)t  * DMODEL))[tid];
  float4 r;
  r.x = e.x + p.x; r.y = e.y + p.y; r.z = e.z + p.z; r.w = e.w + p.w;
  ((float4*)(x + (size_t)bt * DMODEL))[tid] = r;
}

// ------------------------- fp32 -> bf16 convert ---------------------------
__global__ __launch_bounds__(256) void cvt_bf16_kernel(
    const float* __restrict__ in, u16* __restrict__ out) {
  size_t i = ((size_t)blockIdx.x * 256 + threadIdx.x) * 8;
  f32x4 a = __builtin_nontemporal_load((const f32x4*)(in + i));
  f32x4 b = __builtin_nontemporal_load((const f32x4*)(in + i) + 1);
  u16x8 r;
  r[0] = f2bf(a[0]); r[1] = f2bf(a[1]); r[2] = f2bf(a[2]); r[3] = f2bf(a[3]);
  r[4] = f2bf(b[0]); r[5] = f2bf(b[1]); r[6] = f2bf(b[2]); r[7] = f2bf(b[3]);
  *(u16x8*)(out + i) = r;
}

// one launch converts all 4 weight matrices of a layer (6144 blocks)
__global__ __launch_bounds__(256) void cvt4_kernel(
    const float* __restrict__ s0, const float* __restrict__ s1,
    const float* __restrict__ s2, const float* __restrict__ s3,
    u16* __restrict__ d0, u16* __restrict__ d1,
    u16* __restrict__ d2, u16* __restrict__ d3) {
  int bid = blockIdx.x;
  const float* src; u16* dst; int idx;
  if (bid < 1536)      { src = s0; dst = d0; idx = bid; }
  else if (bid < 2048) { src = s1; dst = d1; idx = bid - 1536; }
  else if (bid < 4096) { src = s2; dst = d2; idx = bid - 2048; }
  else                 { src = s3; dst = d3; idx = bid - 4096; }
  size_t i = ((size_t)idx * 256 + threadIdx.x) * 8;
  f32x4 a = __builtin_nontemporal_load((const f32x4*)(src + i));
  f32x4 b = __builtin_nontemporal_load((const f32x4*)(src + i) + 1);
  u16x8 r;
  r[0] = f2bf(a[0]); r[1] = f2bf(a[1]); r[2] = f2bf(a[2]); r[3] = f2bf(a[3]);
  r[4] = f2bf(b[0]); r[5] = f2bf(b[1]); r[6] = f2bf(b[2]); r[7] = f2bf(b[3]);
  *(u16x8*)(dst + i) = r;
}

// ------------------------- layernorm (bf16 out) ---------------------------
__global__ __launch_bounds__(256) void ln_kernel(
    const float* __restrict__ x, const float* __restrict__ g,
    const float* __restrict__ b, u16* __restrict__ y) {
  int row = blockIdx.x, tid = threadIdx.x;
  int lane = tid & 63, w = tid >> 6;
  float4 v = ((const float4*)(x + (size_t)row * DMODEL))[tid];
  float s = v.x + v.y + v.z + v.w;
#pragma unroll
  for (int o = 32; o >= 1; o >>= 1) s += __shfl_xor(s, o);
  __shared__ float red[8];
  if (lane == 0) red[w] = s;
  __syncthreads();
  float mu = (red[0] + red[1] + red[2] + red[3]) * (1.0f / DMODEL);
  float d0 = v.x - mu, d1 = v.y - mu, d2 = v.z - mu, d3 = v.w - mu;
  float s2 = d0*d0 + d1*d1 + d2*d2 + d3*d3;
#pragma unroll
  for (int o = 32; o >= 1; o >>= 1) s2 += __shfl_xor(s2, o);
  if (lane == 0) red[4 + w] = s2;
  __syncthreads();
  float var = (red[4] + red[5] + red[6] + red[7]) * (1.0f / DMODEL);
  float rs = rsqrtf(var + LNEPS);
  float4 gv = ((const float4*)g)[tid];
  float4 bv = ((const float4*)b)[tid];
  u16x4 r;
  r[0] = f2bf(d0 * rs * gv.x + bv.x);
  r[1] = f2bf(d1 * rs * gv.y + bv.y);
  r[2] = f2bf(d2 * rs * gv.z + bv.z);
  r[3] = f2bf(d3 * rs * gv.w + bv.w);
  ((u16x4*)(y + (size_t)row * DMODEL))[tid] = r;
}

__device__ __forceinline__ float gelu_f(float v) {
  return 0.5f * v * (1.0f + erff(v * 0.70710678118654752f));
}

// ------------------- 128x128 MFMA GEMM (small-N cases) ---------------------
template<int ACT, bool BIAS, bool RES, bool OUTBF>
__global__ __launch_bounds__(256) void gemm_mfma(
    const bf16_t* __restrict__ A, const bf16_t* __restrict__ W,
    const float* __restrict__ bias, const float* __restrict__ res,
    void* __restrict__ Cout, int M, int N, int K) {
  __shared__ bf16_t As[128 * 32];
  __shared__ bf16_t Ws[128 * 32];
  const int tid  = threadIdx.x;
  const int lane = tid & 63, w = tid >> 6;
  const int wr = w >> 1, wc = w & 1;

  const int gx  = gridDim.x;
  const int bid = blockIdx.y * gx + blockIdx.x;
  const int cpx = (gx * 32) >> 3;                 // nwg/8 (nwg%8==0)
  const int swz = (bid & 7) * cpx + (bid >> 3);
  const int m0 = (swz & 31) * 128;
  const int n0 = (swz >> 5) * 128;

  const size_t stride = (size_t)K * 2;
  const int srow = lane >> 2;
  const int scol = (lane & 3) * 16;

  const char* gA0 = (const char*)A + ((size_t)(m0 + w * 32 + srow)) * stride + scol;
  const char* gA1 = gA0 + 16 * stride;
  const char* gW0 = (const char*)W + ((size_t)(n0 + w * 32 + srow)) * stride + scol;
  const char* gW1 = gW0 + 16 * stride;
  char* lA0 = (char*)As + (w * 32) * 64;
  char* lA1 = lA0 + 16 * 64;
  char* lW0 = (char*)Ws + (w * 32) * 64;
  char* lW1 = lW0 + 16 * 64;

  f32x4 acc[4][4] = {};

  for (int k0 = 0; k0 < K; k0 += 32) {
    gload16(gA0, lA0); gload16(gA1, lA1);
    gload16(gW0, lW0); gload16(gW1, lW1);
    gA0 += 64; gA1 += 64; gW0 += 64; gW1 += 64;
    __syncthreads();
    bf16x8 afr[4], bfr[4];
    const int kb = (lane >> 4) * 16;
    const int rr = lane & 15;
#pragma unroll
    for (int t = 0; t < 4; ++t) {
      afr[t] = *(const bf16x8*)((const char*)As + (wr * 64 + t * 16 + rr) * 64 + kb);
      bfr[t] = *(const bf16x8*)((const char*)Ws + (wc * 64 + t * 16 + rr) * 64 + kb);
    }
#pragma unroll
    for (int mi = 0; mi < 4; ++mi)
#pragma unroll
      for (int ni = 0; ni < 4; ++ni)
        acc[mi][ni] = __builtin_amdgcn_mfma_f32_16x16x32_bf16(
            afr[mi], bfr[ni], acc[mi][ni], 0, 0, 0);
    __syncthreads();
  }

  const int r4 = (lane >> 4) * 4;
  const int cc = lane & 15;
#pragma unroll
  for (int mi = 0; mi < 4; ++mi) {
#pragma unroll
    for (int ni = 0; ni < 4; ++ni) {
      const int col = n0 + wc * 64 + ni * 16 + cc;
      float bv = 0.f;
      if (BIAS) bv = bias[col];
#pragma unroll
      for (int j = 0; j < 4; ++j) {
        const int row = m0 + wr * 64 + mi * 16 + r4 + j;
        float u = acc[mi][ni][j] + bv;
        if (ACT == 1) u = gelu_f(u);
        if (RES) u += res[(size_t)row * N + col];
        if (OUTBF) ((u16*)Cout)[(size_t)row * N + col] = f2bf(u);
        else       ((float*)Cout)[(size_t)row * N + col] = u;
      }
    }
  }
}

// --------------- 256x256 8-phase MFMA GEMM (big-N cases) -------------------
__device__ __forceinline__ bf16x8 ldsrd(const char* p) {
  return *(const bf16x8*)p;
}

template<int QD>
__device__ __forceinline__ void rd_a(bf16x8 (&afr)[2][2], const char* base,
                                     int aB0, int aB1) {
  afr[0][0] = ldsrd(base + aB0 + QD * 4096);
  afr[0][1] = ldsrd(base + aB1 + QD * 4096);
  afr[1][0] = ldsrd(base + aB0 + QD * 4096 + 2048);
  afr[1][1] = ldsrd(base + aB1 + QD * 4096 + 2048);
}

__device__ __forceinline__ void rd_b(bf16x8 (&bfr)[4][2], const char* base,
                                     int bB0, int bB1) {
#pragma unroll
  for (int ni = 0; ni < 4; ++ni) {
    bfr[ni][0] = ldsrd(base + bB0 + ni * 2048);
    bfr[ni][1] = ldsrd(base + bB1 + ni * 2048);
  }
}

template<int QD>
__device__ __forceinline__ void mm16(f32x4 (&acc)[8][4], bf16x8 (&afr)[2][2],
                                     bf16x8 (&bfr)[4][2]) {
#pragma unroll
  for (int ni = 0; ni < 4; ++ni) {
    acc[QD*2+0][ni] = __builtin_amdgcn_mfma_f32_16x16x32_bf16(afr[0][0], bfr[ni][0], acc[QD*2+0][ni], 0, 0, 0);
    acc[QD*2+0][ni] = __builtin_amdgcn_mfma_f32_16x16x32_bf16(afr[0][1], bfr[ni][1], acc[QD*2+0][ni], 0, 0, 0);
    acc[QD*2+1][ni] = __builtin_amdgcn_mfma_f32_16x16x32_bf16(afr[1][0], bfr[ni][0], acc[QD*2+1][ni], 0, 0, 0);
    acc[QD*2+1][ni] = __builtin_amdgcn_mfma_f32_16x16x32_bf16(afr[1][1], bfr[ni][1], acc[QD*2+1][ni], 0, 0, 0);
  }
}

template<int ACT, bool BIAS, bool OUTBF, bool NT>
__global__ __launch_bounds__(512, 2) void gemm_mfma256(
    const bf16_t* __restrict__ A, const bf16_t* __restrict__ W,
    const float* __restrict__ bias, void* __restrict__ Cout,
    int M, int N, int K) {
  __shared__ char lds[131072];
  char* Asc = lds;
  char* Bsc = lds + 65536;

  const int tid  = threadIdx.x;
  const int lane = tid & 63;
  const int w    = tid >> 6;
  const int wr   = w >> 2, wc = w & 3;

  const int nwg = gridDim.x * gridDim.y;
  const int bid = blockIdx.y * gridDim.x + blockIdx.x;
  const int swz = (bid & 7) * (nwg >> 3) + (bid >> 3);
  const int m0 = (swz & 15) << 8;
  const int n0 = (swz >> 4) << 8;

  const size_t K2 = (size_t)K * 2;
  const int KT = K >> 6;

  const int qsrc = (((tid & 7) ^ ((tid >> 3) & 7)) << 4);
  const char* srcA = (const char*)A + (size_t)(m0 + (tid >> 3)) * K2 + qsrc;
  const char* srcB = (const char*)W + (size_t)(n0 + (tid >> 3)) * K2 + qsrc;
  char* dstA = Asc + (tid & 448) * 16;
  char* dstB = Bsc + (tid & 448) * 16;

  auto STG = [&](int kt, int part) {
    if (kt >= KT) return;
    const int h = part & 1;
    const size_t so = (size_t)(h * 128) * K2 + (size_t)kt * 128;
    const int dofs = ((kt & 1) << 15) + (h << 14);
    if (part >= 2) {
      gload16(srcA + so, dstA + dofs);
      gload16(srcA + so + 64 * K2, dstA + dofs + 8192);
    } else {
      gload16(srcB + so, dstB + dofs);
      gload16(srcB + so + 64 * K2, dstB + dofs + 8192);
    }
  };

  const int rr = lane & 15;
  const int q0 = (((lane >> 4) ^ (lane & 7)) << 4);
  const int aB0 = ((wr << 7) + rr) * 128 + q0;
  const int aB1 = ((wr << 7) + rr) * 128 + (q0 ^ 64);
  const int bB0 = ((wc << 6) + rr) * 128 + q0;
  const int bB1 = ((wc << 6) + rr) * 128 + (q0 ^ 64);

  bf16x8 bfr[4][2];
  bf16x8 afr[2][2];
  f32x4 acc[8][4] = {};

  STG(0, 0); STG(0, 1); STG(0, 2); STG(0, 3);
  STG(1, 0); STG(1, 1);
  WVM4();
  GBAR();

  const int iters = KT >> 1;
  for (int t = 0; t < iters; ++t) {
    const int d = t << 1;
    rd_b(bfr, Bsc, bB0, bB1);
    rd_a<0>(afr, Asc, aB0, aB1);
    STG(d + 1, 2); STG(d + 1, 3);
    GBAR(); WLGKM0();
    __builtin_amdgcn_s_setprio(1); mm16<0>(acc, afr, bfr); __builtin_amdgcn_s_setprio(0);
    GBAR();
    rd_a<1>(afr, Asc, aB0, aB1);
    STG(d + 2, 0);
    GBAR(); WLGKM0();
    __builtin_amdgcn_s_setprio(1); mm16<1>(acc, afr, bfr); __builtin_amdgcn_s_setprio(0);
    GBAR();
    rd_a<2>(afr, Asc, aB0, aB1);
    STG(d + 2, 1);
    GBAR(); WLGKM0();
    __builtin_amdgcn_s_setprio(1); mm16<2>(acc, afr, bfr); __builtin_amdgcn_s_setprio(0);
    GBAR();
    rd_a<3>(afr, Asc, aB0, aB1);
    GBAR(); WLGKM0();
    __builtin_amdgcn_s_setprio(1); mm16<3>(acc, afr, bfr); __builtin_amdgcn_s_setprio(0);
    if (t == iters - 1) { WVM0(); } else { WVM4(); }
    GBAR();
    rd_b(bfr, Bsc + 32768, bB0, bB1);
    rd_a<0>(afr, Asc + 32768, aB0, aB1);
    STG(d + 2, 2);
    GBAR(); WLGKM0();
    __builtin_amdgcn_s_setprio(1); mm16<0>(acc, afr, bfr); __builtin_amdgcn_s_setprio(0);
    GBAR();
    rd_a<1>(afr, Asc + 32768, aB0, aB1);
    STG(d + 2, 3);
    GBAR(); WLGKM0();
    __builtin_amdgcn_s_setprio(1); mm16<1>(acc, afr, bfr); __builtin_amdgcn_s_setprio(0);
    GBAR();
    rd_a<2>(afr, Asc + 32768, aB0, aB1);
    STG(d + 3, 0);
    GBAR(); WLGKM0();
    __builtin_amdgcn_s_setprio(1); mm16<2>(acc, afr, bfr); __builtin_amdgcn_s_setprio(0);
    GBAR();
    rd_a<3>(afr, Asc + 32768, aB0, aB1);
    STG(d + 3, 1);
    GBAR(); WLGKM0();
    __builtin_amdgcn_s_setprio(1); mm16<3>(acc, afr, bfr); __builtin_amdgcn_s_setprio(0);
    WVM4();
    GBAR();
  }

  const int r4 = (lane >> 4) << 2;
  const int cc = lane & 15;
  const int orow0 = m0 + wr * 128;
  const int ocol0 = n0 + wc * 64;
#pragma unroll
  for (int mi = 0; mi < 8; ++mi) {
#pragma unroll
    for (int ni = 0; ni < 4; ++ni) {
      const int col = ocol0 + ni * 16 + cc;
      float bv = 0.f;
      if (BIAS) bv = bias[col];
#pragma unroll
      for (int j = 0; j < 4; ++j) {
        const int row = orow0 + mi * 16 + r4 + j;
        float u = acc[mi][ni][j] + bv;
        if (ACT == 1) u = gelu_f(u);
        if (OUTBF) {
          ((u16*)Cout)[(size_t)row * N + col] = f2bf(u);
        } else if (NT) {
          __builtin_nontemporal_store(u, (float*)Cout + (size_t)row * N + col);
        } else {
          ((float*)Cout)[(size_t)row * N + col] = u;
        }
      }
    }
  }
}

// ----------------------- MFMA flash attention (KVBLK=128) ------------------
// qkv bf16 [B*T, 3*D]; out bf16 [B*T, D]. Block: one (b,h) x 64 q-rows,
// 4 waves x 16 rows. 128-key tiles: K [128][72], V transposed [64][136],
// per-wave P [16][136]. fp32 online softmax once per 128 keys. Register
// prefetch of next tile. Diagonal tiles skip the invalid 64-key half.
__global__ __launch_bounds__(256) void attn_mfma_kernel(
    const u16* __restrict__ qkv, u16* __restrict__ out) {
  const int qb0 = blockIdx.x * 64;
  const int bh  = blockIdx.y;
  const int b = bh >> 4, h = bh & 15;
  const int tid = threadIdx.x;
  const int lane = tid & 63, w = tid >> 6;

  __shared__ u16 Ks[128][72];
  __shared__ u16 Vt[64][136];
  __shared__ u16 Ps[4][16][136];

  const size_t rowstr = 3 * DMODEL;
  const u16* base = qkv + (size_t)b * TSEQ * rowstr;

  const int fr = lane & 15;
  const int fk = (lane >> 4) * 8;
  const int qminw = qb0 + w * 16;
  const int qrow = qminw + fr;

  // Q frags pre-scaled by HD^-0.5
  u16x8 q0r = *(const u16x8*)(base + (size_t)qrow * rowstr + h * HDIM + fk);
  u16x8 q1r = *(const u16x8*)(base + (size_t)qrow * rowstr + h * HDIM + fk + 32);
  bf16x8 qf0, qf1;
#pragma unroll
  for (int i = 0; i < 8; ++i) {
    ((u16*)&qf0)[i] = f2bf(__uint_as_float((unsigned)q0r[i] << 16) * 0.125f);
    ((u16*)&qf1)[i] = f2bf(__uint_as_float((unsigned)q1r[i] << 16) * 0.125f);
  }

  f32x4 o[4] = {};
  float m[4] = {-1e30f, -1e30f, -1e30f, -1e30f};
  float l[4] = {0.f, 0.f, 0.f, 0.f};

  // staging: K row = tid>>1 (0..127), col half = (tid&1)*32
  //          V key pair = (tid&63)*2, dim group = (tid>>6)*16
  const int skr = tid >> 1;
  const int skc = (tid & 1) * 32;
  const int vk0 = (tid & 63) * 2;
  const int vd0 = (tid >> 6) * 16;

  u16x8 k0, k1, k2, k3, va0, va1, vb0, vb1;
  {
    const u16* kr = base + (size_t)skr * rowstr + DMODEL + h * HDIM + skc;
    k0 = *(const u16x8*)kr;        k1 = *(const u16x8*)(kr + 8);
    k2 = *(const u16x8*)(kr + 16); k3 = *(const u16x8*)(kr + 24);
    const u16* vr = base + (size_t)vk0 * rowstr + 2 * DMODEL + h * HDIM + vd0;
    va0 = *(const u16x8*)vr;            va1 = *(const u16x8*)(vr + 8);
    vb0 = *(const u16x8*)(vr + rowstr); vb1 = *(const u16x8*)(vr + rowstr + 8);
  }

  for (int s0 = 0; s0 < qb0 + 64; s0 += 128) {
    __syncthreads();                 // prev-tile LDS reads done
    *(u16x8*)&Ks[skr][skc]      = k0;
    *(u16x8*)&Ks[skr][skc + 8]  = k1;
    *(u16x8*)&Ks[skr][skc + 16] = k2;
    *(u16x8*)&Ks[skr][skc + 24] = k3;
#pragma unroll
    for (int i = 0; i < 8; ++i) {    // pair-packed transpose, conflict-free
      *(unsigned*)&Vt[vd0 + i][vk0]     = (unsigned)va0[i] | ((unsigned)vb0[i] << 16);
      *(unsigned*)&Vt[vd0 + 8 + i][vk0] = (unsigned)va1[i] | ((unsigned)vb1[i] << 16);
    }
    __syncthreads();

    if (s0 + 128 < qb0 + 64) {       // prefetch next tile
      const u16* kr = base + (size_t)(s0 + 128 + skr) * rowstr + DMODEL + h * HDIM + skc;
      k0 = *(const u16x8*)kr;        k1 = *(const u16x8*)(kr + 8);
      k2 = *(const u16x8*)(kr + 16); k3 = *(const u16x8*)(kr + 24);
      const u16* vr = base + (size_t)(s0 + 128 + vk0) * rowstr + 2 * DMODEL + h * HDIM + vd0;
      va0 = *(const u16x8*)vr;            va1 = *(const u16x8*)(vr + 8);
      vb0 = *(const u16x8*)(vr + rowstr); vb1 = *(const u16x8*)(vr + rowstr + 8);
    }

    const bool h2 = s0 < qb0;        // second 64-key half has valid keys

    // QK^T
    f32x4 s[8];
    __builtin_amdgcn_s_setprio(1);
#pragma unroll
    for (int ni = 0; ni < 4; ++ni) {
      f32x4 t = {};
      bf16x8 kf0 = *(const bf16x8*)&Ks[ni * 16 + fr][fk];
      bf16x8 kf1 = *(const bf16x8*)&Ks[ni * 16 + fr][fk + 32];
      t = __builtin_amdgcn_mfma_f32_16x16x32_bf16(qf0, kf0, t, 0, 0, 0);
      t = __builtin_amdgcn_mfma_f32_16x16x32_bf16(qf1, kf1, t, 0, 0, 0);
      s[ni] = t;
    }
    __builtin_amdgcn_s_setprio(0);
    if (h2) {
      __builtin_amdgcn_s_setprio(1);
#pragma unroll
      for (int ni = 4; ni < 8; ++ni) {
        f32x4 t = {};
        bf16x8 kf0 = *(const bf16x8*)&Ks[ni * 16 + fr][fk];
        bf16x8 kf1 = *(const bf16x8*)&Ks[ni * 16 + fr][fk + 32];
        t = __builtin_amdgcn_mfma_f32_16x16x32_bf16(qf0, kf0, t, 0, 0, 0);
        t = __builtin_amdgcn_mfma_f32_16x16x32_bf16(qf1, kf1, t, 0, 0, 0);
        s[ni] = t;
      }
      __builtin_amdgcn_s_setprio(0);
    } else {
#pragma unroll
      for (int ni = 4; ni < 8; ++ni)
        s[ni] = (f32x4){-3e38f, -3e38f, -3e38f, -3e38f};
    }

    if (s0 + 127 > qb0) {            // diagonal region: causal mask
      const int q0_ = qminw + (lane >> 4) * 4;
      const int nl = h2 ? 8 : 4;
#pragma unroll
      for (int ni = 0; ni < 8; ++ni) {
        if (ni >= nl) break;
#pragma unroll
        for (int j = 0; j < 4; ++j)
          if (s0 + ni * 16 + fr > q0_ + j) s[ni][j] = -3e38f;
      }
    }

    // online softmax over 128 keys (rows split across 16-lane groups)
#pragma unroll
    for (int j = 0; j < 4; ++j) {
      float tm = s[0][j];
#pragma unroll
      for (int ni = 1; ni < 8; ++ni) tm = fmaxf(tm, s[ni][j]);
      tm = fmaxf(tm, __shfl_xor(tm, 1));
      tm = fmaxf(tm, __shfl_xor(tm, 2));
      tm = fmaxf(tm, __shfl_xor(tm, 4));
      tm = fmaxf(tm, __shfl_xor(tm, 8));
      float mn = fmaxf(m[j], tm);
      float al = expf(m[j] - mn);
      m[j] = mn;
      float ps = 0.f;
#pragma unroll
      for (int ni = 0; ni < 8; ++ni) {
        float pv = expf(s[ni][j] - mn);
        s[ni][j] = pv;
        ps += pv;
      }
      ps += __shfl_xor(ps, 1);
      ps += __shfl_xor(ps, 2);
      ps += __shfl_xor(ps, 4);
      ps += __shfl_xor(ps, 8);
      l[j] = l[j] * al + ps;
#pragma unroll
      for (int ni = 0; ni < 4; ++ni) o[ni][j] *= al;
    }

    // P -> LDS (bf16), wave-private
    {
      const int nl = h2 ? 8 : 4;
#pragma unroll
      for (int ni = 0; ni < 8; ++ni) {
        if (ni >= nl) break;
#pragma unroll
        for (int j = 0; j < 4; ++j)
          Ps[w][(lane >> 4) * 4 + j][ni * 16 + fr] = f2bf(s[ni][j]);
      }
    }
    WLGKM0();

    // PV: O[q][d] += P[q][key] * V[key][d]
    bf16x8 pf0 = *(const bf16x8*)&Ps[w][fr][fk];
    bf16x8 pf1 = *(const bf16x8*)&Ps[w][fr][fk + 32];
    __builtin_amdgcn_s_setprio(1);
#pragma unroll
    for (int ni = 0; ni < 4; ++ni) {
      bf16x8 vf0 = *(const bf16x8*)&Vt[ni * 16 + fr][fk];
      bf16x8 vf1 = *(const bf16x8*)&Vt[ni * 16 + fr][fk + 32];
      o[ni] = __builtin_amdgcn_mfma_f32_16x16x32_bf16(pf0, vf0, o[ni], 0, 0, 0);
      o[ni] = __builtin_amdgcn_mfma_f32_16x16x32_bf16(pf1, vf1, o[ni], 0, 0, 0);
    }
    __builtin_amdgcn_s_setprio(0);
    if (h2) {
      bf16x8 pf2 = *(const bf16x8*)&Ps[w][fr][64 + fk];
      bf16x8 pf3 = *(const bf16x8*)&Ps[w][fr][96 + fk];
      __builtin_amdgcn_s_setprio(1);
#pragma unroll
      for (int ni = 0; ni < 4; ++ni) {
        bf16x8 vf2 = *(const bf16x8*)&Vt[ni * 16 + fr][64 + fk];
        bf16x8 vf3 = *(const bf16x8*)&Vt[ni * 16 + fr][96 + fk];
        o[ni] = __builtin_amdgcn_mfma_f32_16x16x32_bf16(pf2, vf2, o[ni], 0, 0, 0);
        o[ni] = __builtin_amdgcn_mfma_f32_16x16x32_bf16(pf3, vf3, o[ni], 0, 0, 0);
      }
      __builtin_amdgcn_s_setprio(0);
    }
  }

#pragma unroll
  for (int j = 0; j < 4; ++j) {
    float inv = 1.0f / l[j];
    int q = qminw + (lane >> 4) * 4 + j;
    u16* op = out + ((size_t)(b * TSEQ) + q) * DMODEL + h * HDIM + fr;
#pragma unroll
    for (int ni = 0; ni < 4; ++ni)
      op[ni * 16] = f2bf(o[ni][j] * inv);
  }
}

// ------------------------------ launcher ----------------------------------
extern "C" void kernel_launch(void* const* d_in, const int* in_sizes, int n_in,
                              void* d_out, int out_size, void* d_ws, size_t ws_size,
                              hipStream_t stream) {
  const int*   ids    = (const int*)d_in[0];
  const float* emb    = (const float*)d_in[1];
  const float* pos    = (const float*)d_in[2];
  const float* ln1_g  = (const float*)d_in[3];
  const float* ln1_b  = (const float*)d_in[4];
  const float* ln2_g  = (const float*)d_in[5];
  const float* ln2_b  = (const float*)d_in[6];
  const float* qkv_w  = (const float*)d_in[7];
  const float* out_w  = (const float*)d_in[8];
  const float* mlp_w1 = (const float*)d_in[9];
  const float* mlp_b1 = (const float*)d_in[10];
  const float* mlp_w2 = (const float*)d_in[11];
  const float* mlp_b2 = (const float*)d_in[12];
  const float* lnf_g  = (const float*)d_in[13];
  const float* lnf_b  = (const float*)d_in[14];
  float* outp = (float*)d_out;

  const int M = BATCH * TSEQ;                         // 4096
  char* p = (char*)d_ws;
  float* x    = (float*)p;  p += (size_t)M * DMODEL * 4;
  u16*   yb   = (u16*)p;    p += (size_t)M * DMODEL * 2;
  u16*   qkvb = (u16*)p;    p += (size_t)M * 3 * DMODEL * 2;
  u16*   mid  = (u16*)p;    p += (size_t)M * DFFN * 2;
  u16*   wq   = (u16*)p;    p += (size_t)3 * DMODEL * DMODEL * 2;
  u16*   wo   = (u16*)p;    p += (size_t)DMODEL * DMODEL * 2;
  u16*   w1   = (u16*)p;    p += (size_t)DFFN * DMODEL * 2;
  u16*   w2   = (u16*)p;    p += (size_t)DMODEL * DFFN * 2;
  u16*   embb = qkvb;  // final stage: reuse qkvb+mid+wq/wo (all dead)

  embed_kernel<<<M, 256, 0, stream>>>(ids, emb, pos, x);

  for (int l = 0; l < NLAYER; ++l) {
    cvt4_kernel<<<6144, 256, 0, stream>>>(
        qkv_w  + (size_t)l * 3 * DMODEL * DMODEL,
        out_w  + (size_t)l * DMODEL * DMODEL,
        mlp_w1 + (size_t)l * DFFN * DMODEL,
        mlp_w2 + (size_t)l * DMODEL * DFFN,
        wq, wo, w1, w2);

    ln_kernel<<<M, 256, 0, stream>>>(x, ln1_g + l * DMODEL, ln1_b + l * DMODEL, yb);
    gemm_mfma256<0, false, true, false><<<dim3(3 * DMODEL / 256, M / 256), 512, 0, stream>>>(
        (const bf16_t*)yb, (const bf16_t*)wq, nullptr, qkvb, M, 3 * DMODEL, DMODEL);
    attn_mfma_kernel<<<dim3(TSEQ / 64, BATCH * NHEAD), 256, 0, stream>>>(qkvb, yb);
    gemm_mfma<0, false, true, false><<<dim3(DMODEL / 128, M / 128), 256, 0, stream>>>(
        (const bf16_t*)yb, (const bf16_t*)wo, nullptr, x, x, M, DMODEL, DMODEL);
    ln_kernel<<<M, 256, 0, stream>>>(x, ln2_g + l * DMODEL, ln2_b + l * DMODEL, yb);
    gemm_mfma256<1, true, true, false><<<dim3(DFFN / 256, M / 256), 512, 0, stream>>>(
        (const bf16_t*)yb, (const bf16_t*)w1, mlp_b1 + (size_t)l * DFFN, mid,
        M, DFFN, DMODEL);
    gemm_mfma<0, true, true, false><<<dim3(DMODEL / 128, M / 128), 256, 0, stream>>>(
        (const bf16_t*)mid, (const bf16_t*)w2, mlp_b2 + (size_t)l * DMODEL, x, x,
        M, DMODEL, DFFN);
  }

  ln_kernel<<<M, 256, 0, stream>>>(x, lnf_g, lnf_b, yb);
  cvt_bf16_kernel<<<16000, 256, 0, stream>>>(emb, embb);
  gemm_mfma256<0, false, false, true><<<dim3(NVOCAB / 256, M / 256), 512, 0, stream>>>(
      (const bf16_t*)yb, (const bf16_t*)embb, nullptr, outp, M, NVOCAB, DMODEL);
}

// Round 7
// 2305.582 us; speedup vs baseline: 12.2657x; 1.0843x over previous
//
#include <hip/hip_runtime.h>
#include <math.h>

#define TSEQ   2048
#define BATCH  2
#define DMODEL 1024
#define NLAYER 6
#define NHEAD  16
#define HDIM   64
#define DFFN   4096
#define NVOCAB 32000
#define LNEPS  1e-5f

typedef __bf16 bf16_t;
typedef bf16_t bf16x8 __attribute__((ext_vector_type(8)));
typedef float  f32x4  __attribute__((ext_vector_type(4)));
typedef unsigned short u16;
typedef u16 u16x4 __attribute__((ext_vector_type(4)));
typedef u16 u16x8 __attribute__((ext_vector_type(8)));

#define GBAR()   __builtin_amdgcn_s_barrier()
#define WLGKM0() asm volatile("s_waitcnt lgkmcnt(0)" ::: "memory")
#define WVM4()   asm volatile("s_waitcnt vmcnt(4)" ::: "memory")
#define WVM0()   asm volatile("s_waitcnt vmcnt(0)" ::: "memory")

__device__ __forceinline__ u16 f2bf(float f) {   // RNE fp32 -> bf16 bits
  unsigned u = __float_as_uint(f);
  return (u16)((u + 0x7fffu + ((u >> 16) & 1u)) >> 16);
}

__device__ __forceinline__ void gload16(const void* g, void* l) {
  __builtin_amdgcn_global_load_lds(
      (const __attribute__((address_space(1))) unsigned int*)g,
      (__attribute__((address_space(3))) unsigned int*)l, 16, 0, 0);
}

// ----------------------------- embedding ---------------------------------
__global__ __launch_bounds__(256) void embed_kernel(
    const int* __restrict__ ids, const float* __restrict__ emb,
    const float* __restrict__ pos, float* __restrict__ x) {
  int bt  = blockIdx.x;
  int t   = bt & (TSEQ - 1);
  int id  = ids[bt];
  int tid = threadIdx.x;
  float4 e = ((const float4*)(emb + (size_t)id * DMODEL))[tid];
  float4 p = ((const float4*)(pos + (size_t)t  * DMODEL))[tid];
  float4 r;
  r.x = e.x + p.x; r.y = e.y + p.y; r.z = e.z + p.z; r.w = e.w + p.w;
  ((float4*)(x + (size_t)bt * DMODEL))[tid] = r;
}

// ------------------------- fp32 -> bf16 convert ---------------------------
__global__ __launch_bounds__(256) void cvt_bf16_kernel(
    const float* __restrict__ in, u16* __restrict__ out) {
  size_t i = ((size_t)blockIdx.x * 256 + threadIdx.x) * 8;
  f32x4 a = __builtin_nontemporal_load((const f32x4*)(in + i));
  f32x4 b = __builtin_nontemporal_load((const f32x4*)(in + i) + 1);
  u16x8 r;
  r[0] = f2bf(a[0]); r[1] = f2bf(a[1]); r[2] = f2bf(a[2]); r[3] = f2bf(a[3]);
  r[4] = f2bf(b[0]); r[5] = f2bf(b[1]); r[6] = f2bf(b[2]); r[7] = f2bf(b[3]);
  *(u16x8*)(out + i) = r;
}

// one launch converts all 4 weight matrices of a layer (6144 blocks)
__global__ __launch_bounds__(256) void cvt4_kernel(
    const float* __restrict__ s0, const float* __restrict__ s1,
    const float* __restrict__ s2, const float* __restrict__ s3,
    u16* __restrict__ d0, u16* __restrict__ d1,
    u16* __restrict__ d2, u16* __restrict__ d3) {
  int bid = blockIdx.x;
  const float* src; u16* dst; int idx;
  if (bid < 1536)      { src = s0; dst = d0; idx = bid; }
  else if (bid < 2048) { src = s1; dst = d1; idx = bid - 1536; }
  else if (bid < 4096) { src = s2; dst = d2; idx = bid - 2048; }
  else                 { src = s3; dst = d3; idx = bid - 4096; }
  size_t i = ((size_t)idx * 256 + threadIdx.x) * 8;
  f32x4 a = __builtin_nontemporal_load((const f32x4*)(src + i));
  f32x4 b = __builtin_nontemporal_load((const f32x4*)(src + i) + 1);
  u16x8 r;
  r[0] = f2bf(a[0]); r[1] = f2bf(a[1]); r[2] = f2bf(a[2]); r[3] = f2bf(a[3]);
  r[4] = f2bf(b[0]); r[5] = f2bf(b[1]); r[6] = f2bf(b[2]); r[7] = f2bf(b[3]);
  *(u16x8*)(dst + i) = r;
}

// ------------------------- layernorm (bf16 out) ---------------------------
__global__ __launch_bounds__(256) void ln_kernel(
    const float* __restrict__ x, const float* __restrict__ g,
    const float* __restrict__ b, u16* __restrict__ y) {
  int row = blockIdx.x, tid = threadIdx.x;
  int lane = tid & 63, w = tid >> 6;
  float4 v = ((const float4*)(x + (size_t)row * DMODEL))[tid];
  float s = v.x + v.y + v.z + v.w;
#pragma unroll
  for (int o = 32; o >= 1; o >>= 1) s += __shfl_xor(s, o);
  __shared__ float red[8];
  if (lane == 0) red[w] = s;
  __syncthreads();
  float mu = (red[0] + red[1] + red[2] + red[3]) * (1.0f / DMODEL);
  float d0 = v.x - mu, d1 = v.y - mu, d2 = v.z - mu, d3 = v.w - mu;
  float s2 = d0*d0 + d1*d1 + d2*d2 + d3*d3;
#pragma unroll
  for (int o = 32; o >= 1; o >>= 1) s2 += __shfl_xor(s2, o);
  if (lane == 0) red[4 + w] = s2;
  __syncthreads();
  float var = (red[4] + red[5] + red[6] + red[7]) * (1.0f / DMODEL);
  float rs = rsqrtf(var + LNEPS);
  float4 gv = ((const float4*)g)[tid];
  float4 bv = ((const float4*)b)[tid];
  u16x4 r;
  r[0] = f2bf(d0 * rs * gv.x + bv.x);
  r[1] = f2bf(d1 * rs * gv.y + bv.y);
  r[2] = f2bf(d2 * rs * gv.z + bv.z);
  r[3] = f2bf(d3 * rs * gv.w + bv.w);
  ((u16x4*)(y + (size_t)row * DMODEL))[tid] = r;
}

__device__ __forceinline__ float gelu_f(float v) {
  return 0.5f * v * (1.0f + erff(v * 0.70710678118654752f));
}

// ------------------- 128x128 MFMA GEMM (small-N cases) ---------------------
template<int ACT, bool BIAS, bool RES, bool OUTBF>
__global__ __launch_bounds__(256) void gemm_mfma(
    const bf16_t* __restrict__ A, const bf16_t* __restrict__ W,
    const float* __restrict__ bias, const float* __restrict__ res,
    void* __restrict__ Cout, int M, int N, int K) {
  __shared__ bf16_t As[128 * 32];
  __shared__ bf16_t Ws[128 * 32];
  const int tid  = threadIdx.x;
  const int lane = tid & 63, w = tid >> 6;
  const int wr = w >> 1, wc = w & 1;

  const int gx  = gridDim.x;
  const int bid = blockIdx.y * gx + blockIdx.x;
  const int cpx = (gx * 32) >> 3;                 // nwg/8 (nwg%8==0)
  const int swz = (bid & 7) * cpx + (bid >> 3);
  const int m0 = (swz & 31) * 128;
  const int n0 = (swz >> 5) * 128;

  const size_t stride = (size_t)K * 2;
  const int srow = lane >> 2;
  const int scol = (lane & 3) * 16;

  const char* gA0 = (const char*)A + ((size_t)(m0 + w * 32 + srow)) * stride + scol;
  const char* gA1 = gA0 + 16 * stride;
  const char* gW0 = (const char*)W + ((size_t)(n0 + w * 32 + srow)) * stride + scol;
  const char* gW1 = gW0 + 16 * stride;
  char* lA0 = (char*)As + (w * 32) * 64;
  char* lA1 = lA0 + 16 * 64;
  char* lW0 = (char*)Ws + (w * 32) * 64;
  char* lW1 = lW0 + 16 * 64;

  f32x4 acc[4][4] = {};

  for (int k0 = 0; k0 < K; k0 += 32) {
    gload16(gA0, lA0); gload16(gA1, lA1);
    gload16(gW0, lW0); gload16(gW1, lW1);
    gA0 += 64; gA1 += 64; gW0 += 64; gW1 += 64;
    __syncthreads();
    bf16x8 afr[4], bfr[4];
    const int kb = (lane >> 4) * 16;
    const int rr = lane & 15;
#pragma unroll
    for (int t = 0; t < 4; ++t) {
      afr[t] = *(const bf16x8*)((const char*)As + (wr * 64 + t * 16 + rr) * 64 + kb);
      bfr[t] = *(const bf16x8*)((const char*)Ws + (wc * 64 + t * 16 + rr) * 64 + kb);
    }
#pragma unroll
    for (int mi = 0; mi < 4; ++mi)
#pragma unroll
      for (int ni = 0; ni < 4; ++ni)
        acc[mi][ni] = __builtin_amdgcn_mfma_f32_16x16x32_bf16(
            afr[mi], bfr[ni], acc[mi][ni], 0, 0, 0);
    __syncthreads();
  }

  const int r4 = (lane >> 4) * 4;
  const int cc = lane & 15;
#pragma unroll
  for (int mi = 0; mi < 4; ++mi) {
#pragma unroll
    for (int ni = 0; ni < 4; ++ni) {
      const int col = n0 + wc * 64 + ni * 16 + cc;
      float bv = 0.f;
      if (BIAS) bv = bias[col];
#pragma unroll
      for (int j = 0; j < 4; ++j) {
        const int row = m0 + wr * 64 + mi * 16 + r4 + j;
        float u = acc[mi][ni][j] + bv;
        if (ACT == 1) u = gelu_f(u);
        if (RES) u += res[(size_t)row * N + col];
        if (OUTBF) ((u16*)Cout)[(size_t)row * N + col] = f2bf(u);
        else       ((float*)Cout)[(size_t)row * N + col] = u;
      }
    }
  }
}

// --------------- 256x256 8-phase MFMA GEMM (big-N cases) -------------------
__device__ __forceinline__ bf16x8 ldsrd(const char* p) {
  return *(const bf16x8*)p;
}

template<int QD>
__device__ __forceinline__ void rd_a(bf16x8 (&afr)[2][2], const char* base,
                                     int aB0, int aB1) {
  afr[0][0] = ldsrd(base + aB0 + QD * 4096);
  afr[0][1] = ldsrd(base + aB1 + QD * 4096);
  afr[1][0] = ldsrd(base + aB0 + QD * 4096 + 2048);
  afr[1][1] = ldsrd(base + aB1 + QD * 4096 + 2048);
}

__device__ __forceinline__ void rd_b(bf16x8 (&bfr)[4][2], const char* base,
                                     int bB0, int bB1) {
#pragma unroll
  for (int ni = 0; ni < 4; ++ni) {
    bfr[ni][0] = ldsrd(base + bB0 + ni * 2048);
    bfr[ni][1] = ldsrd(base + bB1 + ni * 2048);
  }
}

template<int QD>
__device__ __forceinline__ void mm16(f32x4 (&acc)[8][4], bf16x8 (&afr)[2][2],
                                     bf16x8 (&bfr)[4][2]) {
#pragma unroll
  for (int ni = 0; ni < 4; ++ni) {
    acc[QD*2+0][ni] = __builtin_amdgcn_mfma_f32_16x16x32_bf16(afr[0][0], bfr[ni][0], acc[QD*2+0][ni], 0, 0, 0);
    acc[QD*2+0][ni] = __builtin_amdgcn_mfma_f32_16x16x32_bf16(afr[0][1], bfr[ni][1], acc[QD*2+0][ni], 0, 0, 0);
    acc[QD*2+1][ni] = __builtin_amdgcn_mfma_f32_16x16x32_bf16(afr[1][0], bfr[ni][0], acc[QD*2+1][ni], 0, 0, 0);
    acc[QD*2+1][ni] = __builtin_amdgcn_mfma_f32_16x16x32_bf16(afr[1][1], bfr[ni][1], acc[QD*2+1][ni], 0, 0, 0);
  }
}

template<int ACT, bool BIAS, bool OUTBF>
__global__ __launch_bounds__(512, 2) void gemm_mfma256(
    const bf16_t* __restrict__ A, const bf16_t* __restrict__ W,
    const float* __restrict__ bias, void* __restrict__ Cout,
    int M, int N, int K) {
  __shared__ char lds[131072];
  char* Asc = lds;
  char* Bsc = lds + 65536;

  const int tid  = threadIdx.x;
  const int lane = tid & 63;
  const int w    = tid >> 6;
  const int wr   = w >> 2, wc = w & 3;

  const int nwg = gridDim.x * gridDim.y;
  const int bid = blockIdx.y * gridDim.x + blockIdx.x;
  const int swz = (bid & 7) * (nwg >> 3) + (bid >> 3);
  const int m0 = (swz & 15) << 8;
  const int n0 = (swz >> 4) << 8;

  const size_t K2 = (size_t)K * 2;
  const int KT = K >> 6;

  const int qsrc = (((tid & 7) ^ ((tid >> 3) & 7)) << 4);
  const char* srcA = (const char*)A + (size_t)(m0 + (tid >> 3)) * K2 + qsrc;
  const char* srcB = (const char*)W + (size_t)(n0 + (tid >> 3)) * K2 + qsrc;
  char* dstA = Asc + (tid & 448) * 16;
  char* dstB = Bsc + (tid & 448) * 16;

  auto STG = [&](int kt, int part) {
    if (kt >= KT) return;
    const int h = part & 1;
    const size_t so = (size_t)(h * 128) * K2 + (size_t)kt * 128;
    const int dofs = ((kt & 1) << 15) + (h << 14);
    if (part >= 2) {
      gload16(srcA + so, dstA + dofs);
      gload16(srcA + so + 64 * K2, dstA + dofs + 8192);
    } else {
      gload16(srcB + so, dstB + dofs);
      gload16(srcB + so + 64 * K2, dstB + dofs + 8192);
    }
  };

  const int rr = lane & 15;
  const int q0 = (((lane >> 4) ^ (lane & 7)) << 4);
  const int aB0 = ((wr << 7) + rr) * 128 + q0;
  const int aB1 = ((wr << 7) + rr) * 128 + (q0 ^ 64);
  const int bB0 = ((wc << 6) + rr) * 128 + q0;
  const int bB1 = ((wc << 6) + rr) * 128 + (q0 ^ 64);

  bf16x8 bfr[4][2];
  bf16x8 afr[2][2];
  f32x4 acc[8][4] = {};

  STG(0, 0); STG(0, 1); STG(0, 2); STG(0, 3);
  STG(1, 0); STG(1, 1);
  WVM4();
  GBAR();

  const int iters = KT >> 1;
  for (int t = 0; t < iters; ++t) {
    const int d = t << 1;
    rd_b(bfr, Bsc, bB0, bB1);
    rd_a<0>(afr, Asc, aB0, aB1);
    STG(d + 1, 2); STG(d + 1, 3);
    GBAR(); WLGKM0();
    __builtin_amdgcn_s_setprio(1); mm16<0>(acc, afr, bfr); __builtin_amdgcn_s_setprio(0);
    GBAR();
    rd_a<1>(afr, Asc, aB0, aB1);
    STG(d + 2, 0);
    GBAR(); WLGKM0();
    __builtin_amdgcn_s_setprio(1); mm16<1>(acc, afr, bfr); __builtin_amdgcn_s_setprio(0);
    GBAR();
    rd_a<2>(afr, Asc, aB0, aB1);
    STG(d + 2, 1);
    GBAR(); WLGKM0();
    __builtin_amdgcn_s_setprio(1); mm16<2>(acc, afr, bfr); __builtin_amdgcn_s_setprio(0);
    GBAR();
    rd_a<3>(afr, Asc, aB0, aB1);
    GBAR(); WLGKM0();
    __builtin_amdgcn_s_setprio(1); mm16<3>(acc, afr, bfr); __builtin_amdgcn_s_setprio(0);
    if (t == iters - 1) { WVM0(); } else { WVM4(); }
    GBAR();
    rd_b(bfr, Bsc + 32768, bB0, bB1);
    rd_a<0>(afr, Asc + 32768, aB0, aB1);
    STG(d + 2, 2);
    GBAR(); WLGKM0();
    __builtin_amdgcn_s_setprio(1); mm16<0>(acc, afr, bfr); __builtin_amdgcn_s_setprio(0);
    GBAR();
    rd_a<1>(afr, Asc + 32768, aB0, aB1);
    STG(d + 2, 3);
    GBAR(); WLGKM0();
    __builtin_amdgcn_s_setprio(1); mm16<1>(acc, afr, bfr); __builtin_amdgcn_s_setprio(0);
    GBAR();
    rd_a<2>(afr, Asc + 32768, aB0, aB1);
    STG(d + 3, 0);
    GBAR(); WLGKM0();
    __builtin_amdgcn_s_setprio(1); mm16<2>(acc, afr, bfr); __builtin_amdgcn_s_setprio(0);
    GBAR();
    rd_a<3>(afr, Asc + 32768, aB0, aB1);
    STG(d + 3, 1);
    GBAR(); WLGKM0();
    __builtin_amdgcn_s_setprio(1); mm16<3>(acc, afr, bfr); __builtin_amdgcn_s_setprio(0);
    WVM4();
    GBAR();
  }

  const int r4 = (lane >> 4) << 2;
  const int cc = lane & 15;
  const int orow0 = m0 + wr * 128;
  const int ocol0 = n0 + wc * 64;
#pragma unroll
  for (int mi = 0; mi < 8; ++mi) {
#pragma unroll
    for (int ni = 0; ni < 4; ++ni) {
      const int col = ocol0 + ni * 16 + cc;
      float bv = 0.f;
      if (BIAS) bv = bias[col];
#pragma unroll
      for (int j = 0; j < 4; ++j) {
        const int row = orow0 + mi * 16 + r4 + j;
        float u = acc[mi][ni][j] + bv;
        if (ACT == 1) u = gelu_f(u);
        if (OUTBF) ((u16*)Cout)[(size_t)row * N + col] = f2bf(u);
        else       ((float*)Cout)[(size_t)row * N + col] = u;
      }
    }
  }
}

// ----------------------- MFMA flash attention (KVBLK=128) ------------------
// Shift-invariant softmax: p = exp(min(s,80) - 8) — exact softmax (o/l) for
// scores < 80, no overflow/underflow (diagonal key guarantees l > 0).
// Row-sum l computed by MFMA with an all-ones B fragment: lsum C-layout rows
// coincide with o's rows, so no cross-lane reduction anywhere.
__global__ __launch_bounds__(256) void attn_mfma_kernel(
    const u16* __restrict__ qkv, u16* __restrict__ out) {
  const int qb0 = blockIdx.x * 64;
  const int bh  = blockIdx.y;
  const int b = bh >> 4, h = bh & 15;
  const int tid = threadIdx.x;
  const int lane = tid & 63, w = tid >> 6;

  __shared__ u16 Ks[128][72];
  __shared__ u16 Vt[64][136];
  __shared__ u16 Ps[4][16][136];

  const size_t rowstr = 3 * DMODEL;
  const u16* base = qkv + (size_t)b * TSEQ * rowstr;

  const int fr = lane & 15;
  const int fk = (lane >> 4) * 8;
  const int qminw = qb0 + w * 16;
  const int qrow = qminw + fr;

  // Q frags pre-scaled by HD^-0.5
  u16x8 q0r = *(const u16x8*)(base + (size_t)qrow * rowstr + h * HDIM + fk);
  u16x8 q1r = *(const u16x8*)(base + (size_t)qrow * rowstr + h * HDIM + fk + 32);
  bf16x8 qf0, qf1;
#pragma unroll
  for (int i = 0; i < 8; ++i) {
    ((u16*)&qf0)[i] = f2bf(__uint_as_float((unsigned)q0r[i] << 16) * 0.125f);
    ((u16*)&qf1)[i] = f2bf(__uint_as_float((unsigned)q1r[i] << 16) * 0.125f);
  }

  bf16x8 onesf;
#pragma unroll
  for (int i = 0; i < 8; ++i) ((u16*)&onesf)[i] = 0x3F80;  // bf16 1.0

  f32x4 o[4] = {};
  f32x4 ls = {};                      // row-sums of P (same row layout as o)

  // staging: K row = tid>>1 (0..127), col half = (tid&1)*32
  //          V key pair = (tid&63)*2, dim group = (tid>>6)*16
  const int skr = tid >> 1;
  const int skc = (tid & 1) * 32;
  const int vk0 = (tid & 63) * 2;
  const int vd0 = (tid >> 6) * 16;

  u16x8 k0, k1, k2, k3, va0, va1, vb0, vb1;
  {
    const u16* kr = base + (size_t)skr * rowstr + DMODEL + h * HDIM + skc;
    k0 = *(const u16x8*)kr;        k1 = *(const u16x8*)(kr + 8);
    k2 = *(const u16x8*)(kr + 16); k3 = *(const u16x8*)(kr + 24);
    const u16* vr = base + (size_t)vk0 * rowstr + 2 * DMODEL + h * HDIM + vd0;
    va0 = *(const u16x8*)vr;            va1 = *(const u16x8*)(vr + 8);
    vb0 = *(const u16x8*)(vr + rowstr); vb1 = *(const u16x8*)(vr + rowstr + 8);
  }

  for (int s0 = 0; s0 < qb0 + 64; s0 += 128) {
    __syncthreads();                 // prev-tile LDS reads done
    *(u16x8*)&Ks[skr][skc]      = k0;
    *(u16x8*)&Ks[skr][skc + 8]  = k1;
    *(u16x8*)&Ks[skr][skc + 16] = k2;
    *(u16x8*)&Ks[skr][skc + 24] = k3;
#pragma unroll
    for (int i = 0; i < 8; ++i) {    // pair-packed transpose, conflict-free
      *(unsigned*)&Vt[vd0 + i][vk0]     = (unsigned)va0[i] | ((unsigned)vb0[i] << 16);
      *(unsigned*)&Vt[vd0 + 8 + i][vk0] = (unsigned)va1[i] | ((unsigned)vb1[i] << 16);
    }
    __syncthreads();

    if (s0 + 128 < qb0 + 64) {       // prefetch next tile
      const u16* kr = base + (size_t)(s0 + 128 + skr) * rowstr + DMODEL + h * HDIM + skc;
      k0 = *(const u16x8*)kr;        k1 = *(const u16x8*)(kr + 8);
      k2 = *(const u16x8*)(kr + 16); k3 = *(const u16x8*)(kr + 24);
      const u16* vr = base + (size_t)(s0 + 128 + vk0) * rowstr + 2 * DMODEL + h * HDIM + vd0;
      va0 = *(const u16x8*)vr;            va1 = *(const u16x8*)(vr + 8);
      vb0 = *(const u16x8*)(vr + rowstr); vb1 = *(const u16x8*)(vr + rowstr + 8);
    }

    const bool h2 = s0 < qb0;        // second 64-key half has valid keys
    const int nl = h2 ? 8 : 4;

    // QK^T
    f32x4 s[8];
    __builtin_amdgcn_s_setprio(1);
#pragma unroll
    for (int ni = 0; ni < 4; ++ni) {
      f32x4 t = {};
      bf16x8 kf0 = *(const bf16x8*)&Ks[ni * 16 + fr][fk];
      bf16x8 kf1 = *(const bf16x8*)&Ks[ni * 16 + fr][fk + 32];
      t = __builtin_amdgcn_mfma_f32_16x16x32_bf16(qf0, kf0, t, 0, 0, 0);
      t = __builtin_amdgcn_mfma_f32_16x16x32_bf16(qf1, kf1, t, 0, 0, 0);
      s[ni] = t;
    }
    __builtin_amdgcn_s_setprio(0);
    if (h2) {
      __builtin_amdgcn_s_setprio(1);
#pragma unroll
      for (int ni = 4; ni < 8; ++ni) {
        f32x4 t = {};
        bf16x8 kf0 = *(const bf16x8*)&Ks[ni * 16 + fr][fk];
        bf16x8 kf1 = *(const bf16x8*)&Ks[ni * 16 + fr][fk + 32];
        t = __builtin_amdgcn_mfma_f32_16x16x32_bf16(qf0, kf0, t, 0, 0, 0);
        t = __builtin_amdgcn_mfma_f32_16x16x32_bf16(qf1, kf1, t, 0, 0, 0);
        s[ni] = t;
      }
      __builtin_amdgcn_s_setprio(0);
    }

    if (s0 + 127 > qb0) {            // causal mask (diagonal region)
      const int q0_ = qminw + (lane >> 4) * 4;
#pragma unroll
      for (int ni = 0; ni < 8; ++ni) {
        if (ni >= nl) break;
#pragma unroll
        for (int j = 0; j < 4; ++j)
          if (s0 + ni * 16 + fr > q0_ + j) s[ni][j] = -3e38f;
      }
    }

    // p = exp(min(s,80) - 8); write P -> LDS (bf16), wave-private
#pragma unroll
    for (int ni = 0; ni < 8; ++ni) {
      if (ni >= nl) break;
#pragma unroll
      for (int j = 0; j < 4; ++j) {
        float pv = __expf(fminf(s[ni][j], 80.f) - 8.f);
        Ps[w][(lane >> 4) * 4 + j][ni * 16 + fr] = f2bf(pv);
      }
    }
    WLGKM0();

    // PV + row-sum: O += P*V ; ls += P*1
    bf16x8 pf0 = *(const bf16x8*)&Ps[w][fr][fk];
    bf16x8 pf1 = *(const bf16x8*)&Ps[w][fr][fk + 32];
    __builtin_amdgcn_s_setprio(1);
#pragma unroll
    for (int ni = 0; ni < 4; ++ni) {
      bf16x8 vf0 = *(const bf16x8*)&Vt[ni * 16 + fr][fk];
      bf16x8 vf1 = *(const bf16x8*)&Vt[ni * 16 + fr][fk + 32];
      o[ni] = __builtin_amdgcn_mfma_f32_16x16x32_bf16(pf0, vf0, o[ni], 0, 0, 0);
      o[ni] = __builtin_amdgcn_mfma_f32_16x16x32_bf16(pf1, vf1, o[ni], 0, 0, 0);
    }
    ls = __builtin_amdgcn_mfma_f32_16x16x32_bf16(pf0, onesf, ls, 0, 0, 0);
    ls = __builtin_amdgcn_mfma_f32_16x16x32_bf16(pf1, onesf, ls, 0, 0, 0);
    __builtin_amdgcn_s_setprio(0);
    if (h2) {
      bf16x8 pf2 = *(const bf16x8*)&Ps[w][fr][64 + fk];
      bf16x8 pf3 = *(const bf16x8*)&Ps[w][fr][96 + fk];
      __builtin_amdgcn_s_setprio(1);
#pragma unroll
      for (int ni = 0; ni < 4; ++ni) {
        bf16x8 vf2 = *(const bf16x8*)&Vt[ni * 16 + fr][64 + fk];
        bf16x8 vf3 = *(const bf16x8*)&Vt[ni * 16 + fr][96 + fk];
        o[ni] = __builtin_amdgcn_mfma_f32_16x16x32_bf16(pf2, vf2, o[ni], 0, 0, 0);
        o[ni] = __builtin_amdgcn_mfma_f32_16x16x32_bf16(pf3, vf3, o[ni], 0, 0, 0);
      }
      ls = __builtin_amdgcn_mfma_f32_16x16x32_bf16(pf2, onesf, ls, 0, 0, 0);
      ls = __builtin_amdgcn_mfma_f32_16x16x32_bf16(pf3, onesf, ls, 0, 0, 0);
      __builtin_amdgcn_s_setprio(0);
    }
  }

#pragma unroll
  for (int j = 0; j < 4; ++j) {
    float inv = 1.0f / ls[j];
    int q = qminw + (lane >> 4) * 4 + j;
    u16* op = out + ((size_t)(b * TSEQ) + q) * DMODEL + h * HDIM + fr;
#pragma unroll
    for (int ni = 0; ni < 4; ++ni)
      op[ni * 16] = f2bf(o[ni][j] * inv);
  }
}

// ------------------------------ launcher ----------------------------------
extern "C" void kernel_launch(void* const* d_in, const int* in_sizes, int n_in,
                              void* d_out, int out_size, void* d_ws, size_t ws_size,
                              hipStream_t stream) {
  const int*   ids    = (const int*)d_in[0];
  const float* emb    = (const float*)d_in[1];
  const float* pos    = (const float*)d_in[2];
  const float* ln1_g  = (const float*)d_in[3];
  const float* ln1_b  = (const float*)d_in[4];
  const float* ln2_g  = (const float*)d_in[5];
  const float* ln2_b  = (const float*)d_in[6];
  const float* qkv_w  = (const float*)d_in[7];
  const float* out_w  = (const float*)d_in[8];
  const float* mlp_w1 = (const float*)d_in[9];
  const float* mlp_b1 = (const float*)d_in[10];
  const float* mlp_w2 = (const float*)d_in[11];
  const float* mlp_b2 = (const float*)d_in[12];
  const float* lnf_g  = (const float*)d_in[13];
  const float* lnf_b  = (const float*)d_in[14];
  float* outp = (float*)d_out;

  const int M = BATCH * TSEQ;                         // 4096
  char* p = (char*)d_ws;
  float* x    = (float*)p;  p += (size_t)M * DMODEL * 4;
  u16*   yb   = (u16*)p;    p += (size_t)M * DMODEL * 2;
  u16*   qkvb = (u16*)p;    p += (size_t)M * 3 * DMODEL * 2;
  u16*   mid  = (u16*)p;    p += (size_t)M * DFFN * 2;
  u16*   wq   = (u16*)p;    p += (size_t)3 * DMODEL * DMODEL * 2;
  u16*   wo   = (u16*)p;    p += (size_t)DMODEL * DMODEL * 2;
  u16*   w1   = (u16*)p;    p += (size_t)DFFN * DMODEL * 2;
  u16*   w2   = (u16*)p;    p += (size_t)DMODEL * DFFN * 2;
  u16*   embb = qkvb;  // final stage: reuse qkvb+mid+wq/wo (all dead)

  embed_kernel<<<M, 256, 0, stream>>>(ids, emb, pos, x);

  for (int l = 0; l < NLAYER; ++l) {
    cvt4_kernel<<<6144, 256, 0, stream>>>(
        qkv_w  + (size_t)l * 3 * DMODEL * DMODEL,
        out_w  + (size_t)l * DMODEL * DMODEL,
        mlp_w1 + (size_t)l * DFFN * DMODEL,
        mlp_w2 + (size_t)l * DMODEL * DFFN,
        wq, wo, w1, w2);

    ln_kernel<<<M, 256, 0, stream>>>(x, ln1_g + l * DMODEL, ln1_b + l * DMODEL, yb);
    gemm_mfma256<0, false, true><<<dim3(3 * DMODEL / 256, M / 256), 512, 0, stream>>>(
        (const bf16_t*)yb, (const bf16_t*)wq, nullptr, qkvb, M, 3 * DMODEL, DMODEL);
    attn_mfma_kernel<<<dim3(TSEQ / 64, BATCH * NHEAD), 256, 0, stream>>>(qkvb, yb);
    gemm_mfma<0, false, true, false><<<dim3(DMODEL / 128, M / 128), 256, 0, stream>>>(
        (const bf16_t*)yb, (const bf16_t*)wo, nullptr, x, x, M, DMODEL, DMODEL);
    ln_kernel<<<M, 256, 0, stream>>>(x, ln2_g + l * DMODEL, ln2_b + l * DMODEL, yb);
    gemm_mfma256<1, true, true><<<dim3(DFFN / 256, M / 256), 512, 0, stream>>>(
        (const bf16_t*)yb, (const bf16_t*)w1, mlp_b1 + (size_t)l * DFFN, mid,
        M, DFFN, DMODEL);
    gemm_mfma<0, true, true, false><<<dim3(DMODEL / 128, M / 128), 256, 0, stream>>>(
        (const bf16_t*)mid, (const bf16_t*)w2, mlp_b2 + (size_t)l * DMODEL, x, x,
        M, DMODEL, DFFN);
  }

  ln_kernel<<<M, 256, 0, stream>>>(x, lnf_g, lnf_b, yb);
  cvt_bf16_kernel<<<16000, 256, 0, stream>>>(emb, embb);
  gemm_mfma256<0, false, false><<<dim3(NVOCAB / 256, M / 256), 512, 0, stream>>>(
      (const bf16_t*)yb, (const bf16_t*)embb, nullptr, outp, M, NVOCAB, DMODEL);
}